// Round 5
// baseline (5119.299 us; speedup 1.0000x reference)
//
#include <hip/hip_runtime.h>
#include <hip/hip_bf16.h>

typedef __bf16 bf16;
typedef __bf16 bf16x8 __attribute__((ext_vector_type(8)));
typedef float floatx4 __attribute__((ext_vector_type(4)));
typedef float floatx16 __attribute__((ext_vector_type(16)));
typedef unsigned long long u64;

#define TSEQ 512
#define MFMA16 __builtin_amdgcn_mfma_f32_16x16x32_bf16

__device__ __forceinline__ float sigm(float x){ return 1.0f/(1.0f + __expf(-x)); }
__device__ __forceinline__ float tanh_fast(float x){
    float e = __expf(2.0f*x);
    return 1.0f - 2.0f/(e + 1.0f);   // correct limits at +-inf
}

// fp32 -> bf16 converter
__global__ __launch_bounds__(256, 4)
void f2b_kernel(const float* __restrict__ in, bf16* __restrict__ out, int n)
{
    int i = blockIdx.x*256 + threadIdx.x;
    if (i < n) out[i] = (bf16)in[i];
}

// ---------------------------------------------------------------------------
// Pack Whh (1024 x 256 fp32) into MFMA-16x16x32 B-frag-major bf16 layout:
// Wp[ntile 0..63][kstep 0..7][lane 0..63][e 0..7], value =
//   Whh[gatecol = ntile*16 + (lane&15)][k = kstep*32 + (lane>>4)*8 + e]
// ---------------------------------------------------------------------------
__global__ __launch_bounds__(256, 4)
void pack_whh(const float* __restrict__ whh, bf16* __restrict__ wp)
{
    int idx = blockIdx.x*256 + threadIdx.x;
    if (idx >= 32768) return;
    int lane = idx & 63, ks = (idx >> 6) & 7, nt = idx >> 9;
    int row = nt*16 + (lane & 15);
    int k0  = ks*32 + (lane >> 4)*8;
    const float* src = whh + (size_t)row*256 + k0;
    bf16x8 v;
    #pragma unroll
    for (int e = 0; e < 8; e++) v[e] = (bf16)src[e];
    ((bf16x8*)wp)[idx] = v;
}

// ---------------------------------------------------------------------------
// xg = x @ Wih^T + bias for one 256-step chunk, both dirs (blockIdx.z).
// Output layout (rec-matched, broadcast-friendly):
//   xg[blk = d*16 + seq/4][sloc][w 0..7][j 0..7][l15 0..15][r = seq&3] fp32
// i.e. plane of 16 KiB per (blk, sloc); rec thread (w,l15) loads float4 at
// ((w*8+j)*16+l15)*16 — 16 consecutive float4s per (w,j), lq-broadcast.
// ---------------------------------------------------------------------------
template<int DIN, bool XF32>
__global__ __launch_bounds__(256, 2)
void xg_gemm(const void* __restrict__ xin,
             const bf16* __restrict__ wbf, const bf16* __restrict__ wbb,
             const float* __restrict__ bf_, const float* __restrict__ bb_,
             float* __restrict__ xg, int chunk)
{
    __shared__ char smem[64*144*2];
    const int tid = threadIdx.x;
    const int wv = tid >> 6, ln = tid & 63;
    const int mi = wv & 1, ni = wv >> 1;
    const int l31 = ln & 31, lh = ln >> 5;
    char* At = smem;
    char* Bt = smem + 64*144;

    const int d   = blockIdx.z;
    const int seq = blockIdx.x >> 2;
    const int tb  = blockIdx.x & 3;
    const int n0  = blockIdx.y * 64;
    const bf16*  wb   = d ? wbb : wbf;
    const float* bias = d ? bb_ : bf_;
    const int sl0 = tb*64;
    const int t0  = d ? (511 - (chunk*256 + sl0)) : (chunk*256 + sl0);
    const int stp = d ? -1 : 1;

    floatx16 acc;
    #pragma unroll
    for (int r = 0; r < 16; r++) acc[r] = 0.0f;

    for (int kc = 0; kc < DIN; kc += 64) {
        __syncthreads();
        for (int c = tid; c < 1024; c += 256) {
            const int which = c >> 9, idx = c & 511;
            const int row = idx >> 3, k8 = idx & 7;
            if (which == 0) {
                const int trow = t0 + row*stp;
                if constexpr (XF32) {
                    const float* src = (const float*)xin
                        + ((size_t)seq*TSEQ + trow)*DIN + kc + k8*8;
                    const float4 lo = *(const float4*)src;
                    const float4 hi = *(const float4*)(src+4);
                    bf16 tmp[8] = {(bf16)lo.x,(bf16)lo.y,(bf16)lo.z,(bf16)lo.w,
                                   (bf16)hi.x,(bf16)hi.y,(bf16)hi.z,(bf16)hi.w};
                    *(uint4*)(At + row*144 + k8*16) = *(uint4*)tmp;
                } else {
                    const bf16* src = (const bf16*)xin
                        + ((size_t)seq*TSEQ + trow)*DIN + kc + k8*8;
                    *(uint4*)(At + row*144 + k8*16) = *(const uint4*)src;
                }
            } else {
                *(uint4*)(Bt + row*144 + k8*16) =
                    *(const uint4*)(wb + (size_t)(n0+row)*DIN + kc + k8*8);
            }
        }
        __syncthreads();
        #pragma unroll
        for (int ks = 0; ks < 4; ks++) {
            bf16x8 a = *(const bf16x8*)(At + (mi*32 + l31)*144 + ks*32 + lh*16);
            bf16x8 b = *(const bf16x8*)(Bt + (ni*32 + l31)*144 + ks*32 + lh*16);
            acc = __builtin_amdgcn_mfma_f32_32x32x16_bf16(a, b, acc, 0, 0, 0);
        }
    }
    const int col = n0 + ni*32 + l31;
    const float bv = bias[col];
    const int nt = col >> 4, l15c = col & 15;
    const int wq = nt & 7, jq = nt >> 3;
    char* pbase = (char*)xg
        + ((size_t)(d*16 + (seq >> 2))*256)*16384
        + (size_t)(((wq*8 + jq)*16 + l15c)*16 + (seq & 3)*4);
    #pragma unroll
    for (int r = 0; r < 16; r++) {
        const int rowl = mi*32 + (r&3) + 8*(r>>2) + 4*lh;
        *(float*)(pbase + (size_t)(sl0 + rowl)*16384) = acc[r] + bv;
    }
}

// ---------------------------------------------------------------------------
// Batch-split recurrence v5. 32 blocks = 2 dir x 16 groups of 4 seqs; 512 thr
// (8 waves, 2/SIMD). Zero inter-block traffic. Per wave: 8 ntiles nt=j*8+w:
//   j=0..4 reg-resident WR (160 VGPR), j=5,6 LDS (16 ntiles, 128 KiB),
//   j=7 streamed from L2 (SB, refilled per step).
// A rows alias x4 (l15&3) -> A ds_reads are 4-way broadcast (bank-cheap);
// all 64 lanes produce valid gates (xg C-in lq-broadcast), no divergence.
// Gate j-map: j0,1=i  j2,3=f  j4,5=g  j6,7=o; cell (seq r, hcol=(jj*8+w)*16+l15)
// with jj = lq>>1 (4 cells/thread); even-lq -> LDS h store, odd-lq -> global.
// ONE barrier per step. xg C-in refilled as 8 coalesced float4 broadcasts.
// ---------------------------------------------------------------------------
__global__ __launch_bounds__(512, 1)
void rec_kernel(const float* __restrict__ xg,
                const bf16* __restrict__ WpF, const bf16* __restrict__ WpB,
                bf16* __restrict__ hsout, float* __restrict__ cst, int chunk)
{
    extern __shared__ char smem[];
    bf16x8* Wlds = (bf16x8*)smem;            // ntiles 40..55 = 8192 frags = 128 KiB
    char* hb0 = smem + 131072;               // 4 rows x 544 B
    char* hb1 = hb0 + 2176;

    const int tid = threadIdx.x;
    const int w = tid >> 6, l = tid & 63;
    const int l15 = l & 15, lq = l >> 4;
    const int blk = blockIdx.x;
    const int d = blk >> 4, bg = blk & 15;
    const bf16x8* Wp = (const bf16x8*)(d ? WpB : WpF);

    // LDS tier: ntiles 40..55 (j=5,6 for all waves)
    for (int i = tid; i < 8192; i += 512) Wlds[i] = Wp[40*512 + i];

    // reg tier j=0..4 (nt = j*8+w)
    bf16x8 WR[5][8];
    #pragma unroll
    for (int j = 0; j < 5; j++)
        #pragma unroll
        for (int ks = 0; ks < 8; ks++)
            WR[j][ks] = Wp[((j*8 + w)*8 + ks)*64 + l];
    // streamed tier j=7 (nt = 56+w)
    const int sbBase = ((56 + w)*8)*64 + l;
    bf16x8 SB[8];
    #pragma unroll
    for (int ks = 0; ks < 8; ks++) SB[ks] = Wp[sbBase + ks*64];

    // h buffer init (reads always start from hb0: chunk*256 is even)
    if (chunk == 0) {
        if (tid < 136) ((uint4*)hb0)[tid] = make_uint4(0,0,0,0);
    } else {
        if (tid < 128) {
            const int tprev = d ? (512 - chunk*256) : (chunk*256 - 1);
            const int row = tid >> 5, c8 = (tid & 31)*8;
            uint4 v = *(const uint4*)(hsout
                + ((size_t)(bg*4 + row)*TSEQ + tprev)*512 + d*256 + c8);
            *(uint4*)(hb0 + row*544 + c8*2) = v;
        }
    }

    // c-state: 4 cells (seq r, hcol=(jj*8+w)*16+l15), jj=lq>>1, dup x2 over lq&1
    float cs[4];
    if (chunk == 0) { cs[0]=cs[1]=cs[2]=cs[3]=0.0f; }
    else {
        float4 cv = ((const float4*)cst)[blk*512 + tid];
        cs[0]=cv.x; cs[1]=cv.y; cs[2]=cv.z; cs[3]=cv.w;
    }

    // xg plane base + per-(w,j,l15) offsets
    const char* xgp = (const char*)xg + ((size_t)blk*256)*16384;
    floatx4 acc[8];
    #pragma unroll
    for (int j = 0; j < 8; j++)
        acc[j] = *(const floatx4*)(xgp + ((w*8 + j)*16 + l15)*16);

    __syncthreads();

    const int aoff = (l15 & 3)*544 + lq*16;
    const int i5b = w*512 + l;            // Wlds idx base j=5 (+ks*64)
    const int i6b = (8 + w)*512 + l;      // j=6
    const bool hi2 = (lq >= 2);
    const int hcol = ((hi2 ? 8 : 0) + w)*16 + l15;
    const size_t hgbase = (size_t)(bg*4)*TSEQ*512 + d*256 + hcol;

    for (int sl = 0; sl < 256; ++sl) {
        const int s = chunk*256 + sl;
        const int t = d ? (511 - s) : s;
        const char* hr = (sl & 1) ? hb1 : hb0;
        char* hw = (sl & 1) ? hb0 : hb1;

        // ---- MFMA: gates = xg + h_prev @ Whh^T ----
        bf16x8 Ac = *(const bf16x8*)(hr + aoff);
        #pragma unroll
        for (int ks = 0; ks < 8; ks++) {
            bf16x8 An = Ac;
            if (ks < 7) An = *(const bf16x8*)(hr + aoff + (ks+1)*64);
            acc[0] = MFMA16(Ac, WR[0][ks], acc[0], 0,0,0);
            acc[1] = MFMA16(Ac, WR[1][ks], acc[1], 0,0,0);
            acc[2] = MFMA16(Ac, WR[2][ks], acc[2], 0,0,0);
            acc[3] = MFMA16(Ac, WR[3][ks], acc[3], 0,0,0);
            acc[4] = MFMA16(Ac, WR[4][ks], acc[4], 0,0,0);
            acc[5] = MFMA16(Ac, Wlds[i5b + ks*64], acc[5], 0,0,0);
            acc[6] = MFMA16(Ac, Wlds[i6b + ks*64], acc[6], 0,0,0);
            acc[7] = MFMA16(Ac, SB[ks], acc[7], 0,0,0);
            Ac = An;
        }
        // refill streamed tier for next step (full-step latency cover)
        int zx;
        asm volatile("s_mov_b32 %0, 0" : "=s"(zx));
        #pragma unroll
        for (int ks = 0; ks < 8; ks++) SB[ks] = Wp[sbBase + ks*64 + zx];

        // ---- phase A: extract i,f; refill acc[0..3]; sigmoids ----
        float pI[4], pF[4];
        #pragma unroll
        for (int r = 0; r < 4; r++) {
            pI[r] = hi2 ? acc[1][r] : acc[0][r];
            pF[r] = hi2 ? acc[3][r] : acc[2][r];
        }
        if (sl < 255) {
            const char* xp = xgp + (size_t)(sl + 1)*16384;
            #pragma unroll
            for (int j = 0; j < 4; j++)
                acc[j] = *(const floatx4*)(xp + ((w*8 + j)*16 + l15)*16);
        }
        #pragma unroll
        for (int r = 0; r < 4; r++) { pI[r] = sigm(pI[r]); pF[r] = sigm(pF[r]); }

        // ---- phase B: extract g,o; refill acc[4..7]; cell math ----
        float gG[4], gO[4];
        #pragma unroll
        for (int r = 0; r < 4; r++) {
            gG[r] = hi2 ? acc[5][r] : acc[4][r];
            gO[r] = hi2 ? acc[7][r] : acc[6][r];
        }
        if (sl < 255) {
            const char* xp = xgp + (size_t)(sl + 1)*16384;
            #pragma unroll
            for (int j = 4; j < 8; j++)
                acc[j] = *(const floatx4*)(xp + ((w*8 + j)*16 + l15)*16);
        }
        float hv[4];
        #pragma unroll
        for (int r = 0; r < 4; r++) {
            const float cn = pF[r]*cs[r] + pI[r]*tanh_fast(gG[r]);
            cs[r] = cn;
            hv[r] = sigm(gO[r])*tanh_fast(cn);
        }

        // ---- h stores: even-lq -> LDS (next A), odd-lq -> global hsout ----
        if ((lq & 1) == 0) {
            #pragma unroll
            for (int r = 0; r < 4; r++)
                *(bf16*)(hw + r*544 + hcol*2) = (bf16)hv[r];
        } else {
            bf16* hgp = hsout + hgbase + (size_t)t*512;
            #pragma unroll
            for (int r = 0; r < 4; r++)
                hgp[(size_t)r*TSEQ*512] = (bf16)hv[r];
        }
        __syncthreads();
    }

    ((float4*)cst)[blk*512 + tid] = make_float4(cs[0], cs[1], cs[2], cs[3]);
}

// ---------------------------------------------------------------------------
// Shared 64x64 bf16 GEMM main loop (attention chain) — unchanged.
// ---------------------------------------------------------------------------
__device__ __forceinline__ floatx16 gemm_loop(const bf16* __restrict__ A0,
                                              const bf16* __restrict__ Bt0,
                                              int lda, int ldb, int K, int brows,
                                              char* smem)
{
    const int tid = threadIdx.x;
    const int wave = tid >> 6, lane = tid & 63;
    const int mi = wave & 1, ni = wave >> 1;
    const int l31 = lane & 31, lh = lane >> 5;
    char* At = smem;
    char* Bt = smem + 64*144;
    floatx16 acc;
    #pragma unroll
    for (int r = 0; r < 16; r++) acc[r] = 0.0f;

    for (int kc = 0; kc < K; kc += 64) {
        __syncthreads();
        for (int c = tid; c < 1024; c += 256) {
            int which = c >> 9;
            int idx = c & 511;
            int row = idx >> 3, kch = idx & 7;
            uint4 v;
            if (which == 0) {
                v = *(const uint4*)(A0 + (size_t)row*lda + kc + kch*8);
                *(uint4*)(At + row*144 + kch*16) = v;
            } else {
                if (row < brows) v = *(const uint4*)(Bt0 + (size_t)row*ldb + kc + kch*8);
                else             v = make_uint4(0,0,0,0);
                *(uint4*)(Bt + row*144 + kch*16) = v;
            }
        }
        __syncthreads();
        #pragma unroll
        for (int ks = 0; ks < 4; ks++) {
            bf16x8 a = *(const bf16x8*)(At + (mi*32 + l31)*144 + ks*32 + lh*16);
            bf16x8 b = *(const bf16x8*)(Bt + (ni*32 + l31)*144 + ks*32 + lh*16);
            acc = __builtin_amdgcn_mfma_f32_32x32x16_bf16(a, b, acc, 0, 0, 0);
        }
    }
    return acc;
}

__global__ __launch_bounds__(256, 2)
void sgemm_scores(const bf16* __restrict__ hs1, float* __restrict__ S)
{
    __shared__ char smem[64*144*2];
    int n = blockIdx.z, tm = blockIdx.x, tn = blockIdx.y;
    const bf16* base = hs1 + (size_t)n*512*512;
    floatx16 acc = gemm_loop(base + (size_t)tm*64*512, base + (size_t)tn*64*512,
                             512, 512, 512, 64, smem);
    int wave = threadIdx.x >> 6, lane = threadIdx.x & 63;
    int mi = wave & 1, ni = wave >> 1;
    #pragma unroll
    for (int r = 0; r < 16; r++) {
        int row = tm*64 + mi*32 + (r&3) + 8*(r>>2) + 4*(lane>>5);
        int col = tn*64 + ni*32 + (lane&31);
        S[(size_t)n*512*512 + (size_t)row*512 + col] = acc[r];
    }
}

__global__ __launch_bounds__(256, 4)
void softmax_rows(const float* __restrict__ S, bf16* __restrict__ P)
{
    int row = blockIdx.x*4 + (threadIdx.x >> 6);
    int lane = threadIdx.x & 63;
    const float* src = S + (size_t)row*512 + lane*8;
    float4 a = *(const float4*)(src);
    float4 b = *(const float4*)(src + 4);
    float v[8] = {a.x,a.y,a.z,a.w,b.x,b.y,b.z,b.w};
    float m = v[0];
    #pragma unroll
    for (int j = 1; j < 8; j++) m = fmaxf(m, v[j]);
    #pragma unroll
    for (int off = 32; off > 0; off >>= 1) m = fmaxf(m, __shfl_xor(m, off));
    float s = 0.0f;
    #pragma unroll
    for (int j = 0; j < 8; j++) { v[j] = __expf(v[j]-m); s += v[j]; }
    #pragma unroll
    for (int off = 32; off > 0; off >>= 1) s += __shfl_xor(s, off);
    float inv = 1.0f/s;
    union { uint4 u; bf16 h[8]; } pk;
    #pragma unroll
    for (int j = 0; j < 8; j++) pk.h[j] = (bf16)(v[j]*inv);
    *(uint4*)(P + (size_t)row*512 + lane*8) = pk.u;
}

__global__ __launch_bounds__(256, 2)
void transpose_nt(const bf16* __restrict__ hs1, bf16* __restrict__ hs1T)
{
    __shared__ bf16 tile[64][72];
    int n = blockIdx.z, tX = blockIdx.x, fX = blockIdx.y;
    const bf16* src = hs1 + (size_t)n*512*512;
    for (int c = threadIdx.x; c < 512; c += 256) {
        int row = c >> 3, kch = c & 7;
        *(uint4*)(&tile[row][kch*8]) =
            *(const uint4*)(src + (size_t)(tX*64+row)*512 + fX*64 + kch*8);
    }
    __syncthreads();
    bf16* dst = hs1T + (size_t)n*512*512;
    for (int c = threadIdx.x; c < 512; c += 256) {
        int frow = c >> 3, tch = c & 7;
        bf16 tmp[8];
        #pragma unroll
        for (int j = 0; j < 8; j++) tmp[j] = tile[tch*8+j][frow];
        *(uint4*)(dst + (size_t)(fX*64+frow)*512 + tX*64 + tch*8) = *(uint4*)tmp;
    }
}

__global__ __launch_bounds__(256, 2)
void ctx_gemm(const bf16* __restrict__ P, const bf16* __restrict__ hs1T,
              bf16* __restrict__ ctx)
{
    __shared__ char smem[64*144*2];
    int n = blockIdx.z, tm = blockIdx.x, tn = blockIdx.y;
    const bf16* A0 = P    + (size_t)n*512*512 + (size_t)tm*64*512;
    const bf16* B0 = hs1T + (size_t)n*512*512 + (size_t)tn*64*512;
    floatx16 acc = gemm_loop(A0, B0, 512, 512, 512, 64, smem);
    int wave = threadIdx.x >> 6, lane = threadIdx.x & 63;
    int mi = wave & 1, ni = wave >> 1;
    #pragma unroll
    for (int r = 0; r < 16; r++) {
        int row = tm*64 + mi*32 + (r&3) + 8*(r>>2) + 4*(lane>>5);
        int col = tn*64 + ni*32 + (lane&31);
        ctx[((size_t)n*512 + row)*512 + col] = (bf16)acc[r];
    }
}

__global__ __launch_bounds__(256, 2)
void fc1_gemm(const bf16* __restrict__ ctx, const bf16* __restrict__ hs1,
              const bf16* __restrict__ wb, const float* __restrict__ b,
              float* __restrict__ outp)
{
    __shared__ char smem[64*144*2];
    const int tid = threadIdx.x;
    const int wave = tid >> 6, lane = tid & 63;
    const int mi = wave & 1, ni = wave >> 1;
    const int l31 = lane & 31, lh = lane >> 5;
    char* At = smem;
    char* Bt = smem + 64*144;
    const int m0 = blockIdx.x*64;
    floatx16 acc;
    #pragma unroll
    for (int r = 0; r < 16; r++) acc[r] = 0.0f;

    for (int kc = 0; kc < 1024; kc += 64) {
        const bf16* Asrc = (kc < 512) ? ctx : hs1;
        const int koff = kc & 511;
        __syncthreads();
        for (int c = tid; c < 1024; c += 256) {
            int which = c >> 9, idx = c & 511;
            int row = idx >> 3, kch = idx & 7;
            uint4 v;
            if (which == 0) {
                v = *(const uint4*)(Asrc + (size_t)(m0+row)*512 + koff + kch*8);
                *(uint4*)(At + row*144 + kch*16) = v;
            } else {
                if (row < 50) v = *(const uint4*)(wb + (size_t)row*1024 + kc + kch*8);
                else          v = make_uint4(0,0,0,0);
                *(uint4*)(Bt + row*144 + kch*16) = v;
            }
        }
        __syncthreads();
        #pragma unroll
        for (int ks = 0; ks < 4; ks++) {
            bf16x8 a = *(const bf16x8*)(At + (mi*32 + l31)*144 + ks*32 + lh*16);
            bf16x8 bb = *(const bf16x8*)(Bt + (ni*32 + l31)*144 + ks*32 + lh*16);
            acc = __builtin_amdgcn_mfma_f32_32x32x16_bf16(a, bb, acc, 0, 0, 0);
        }
    }
    #pragma unroll
    for (int r = 0; r < 16; r++) {
        int row = m0 + mi*32 + (r&3) + 8*(r>>2) + 4*lh;
        int col = ni*32 + l31;
        if (col < 50) {
            float v = acc[r] + b[col];
            outp[(size_t)row*50 + col] = fmaxf(v, 0.0f);
        }
    }
}

__global__ __launch_bounds__(256, 4)
void bn_stats(const float* __restrict__ fc1out, float* __restrict__ stats)
{
    __shared__ float sh[512];
    int c = blockIdx.x;
    float s = 0.0f, ss = 0.0f;
    for (int i = threadIdx.x; i < 32768; i += 256) {
        int n = i >> 9, q = i & 511;
        float x = fc1out[(size_t)n*25600 + c*512 + q];
        s += x; ss += x*x;
    }
    sh[threadIdx.x] = s; sh[256 + threadIdx.x] = ss;
    __syncthreads();
    for (int o = 128; o > 0; o >>= 1) {
        if (threadIdx.x < o) {
            sh[threadIdx.x] += sh[threadIdx.x + o];
            sh[256+threadIdx.x] += sh[256+threadIdx.x + o];
        }
        __syncthreads();
    }
    if (threadIdx.x == 0) {
        float mean = sh[0] / 32768.0f;
        float var  = sh[256] / 32768.0f - mean*mean;
        stats[c]      = mean;
        stats[64 + c] = rsqrtf(var + 1e-5f);
    }
}

__global__ __launch_bounds__(256, 4)
void tail_kernel(const float* __restrict__ fc1out, const float* __restrict__ stats,
                 const float* __restrict__ bng, const float* __restrict__ bnb,
                 const float* __restrict__ fc2w, const float* __restrict__ fc2b,
                 const float* __restrict__ fc3w, const float* __restrict__ fc3b,
                 const float* __restrict__ fc4w, const float* __restrict__ fc4b,
                 float* __restrict__ outp)
{
    __shared__ float W2[1250], W3[250], B2[25], B3[10], W4[20], B4[2];
    __shared__ float G[50], Bb[50], MU[50], IS[50];
    for (int i = threadIdx.x; i < 1250; i += 256) W2[i] = fc2w[i];
    for (int i = threadIdx.x; i < 250;  i += 256) W3[i] = fc3w[i];
    if (threadIdx.x < 25) B2[threadIdx.x] = fc2b[threadIdx.x];
    if (threadIdx.x < 20) W4[threadIdx.x] = fc4w[threadIdx.x];
    if (threadIdx.x < 10) B3[threadIdx.x] = fc3b[threadIdx.x];
    if (threadIdx.x < 2)  B4[threadIdx.x] = fc4b[threadIdx.x];
    if (threadIdx.x < 50) {
        G[threadIdx.x]  = bng[threadIdx.x];
        Bb[threadIdx.x] = bnb[threadIdx.x];
        MU[threadIdx.x] = stats[threadIdx.x];
        IS[threadIdx.x] = stats[64 + threadIdx.x];
    }
    __syncthreads();
    int m = blockIdx.x*256 + threadIdx.x;
    int t = m & 511;
    const float* src = fc1out + (size_t)m*50;
    float x[50];
    #pragma unroll
    for (int c = 0; c < 50; c++) {
        int j = (t*50 + c) >> 9;
        x[c] = (src[c] - MU[j])*IS[j]*G[j] + Bb[j];
    }
    float y2[25];
    #pragma unroll
    for (int o = 0; o < 25; o++) {
        float a = B2[o];
        for (int c = 0; c < 50; c++) a += x[c]*W2[o*50+c];
        y2[o] = fmaxf(a, 0.0f);
    }
    float y3[10];
    #pragma unroll
    for (int o = 0; o < 10; o++) {
        float a = B3[o];
        for (int c = 0; c < 25; c++) a += y2[c]*W3[o*25+c];
        y3[o] = fmaxf(a, 0.0f);
    }
    #pragma unroll
    for (int o = 0; o < 2; o++) {
        float a = B4[o];
        for (int c = 0; c < 10; c++) a += y3[c]*W4[o*10+c];
        outp[(size_t)m*2 + o] = a;
    }
}

extern "C" void kernel_launch(void* const* d_in, const int* in_sizes, int n_in,
                              void* d_out, int out_size, void* d_ws, size_t ws_size,
                              hipStream_t stream)
{
    const float* x       = (const float*)d_in[0];
    const float* wih_l0f = (const float*)d_in[1];
    const float* whh_l0f = (const float*)d_in[2];
    const float* b_l0f   = (const float*)d_in[3];
    const float* wih_l0b = (const float*)d_in[4];
    const float* whh_l0b = (const float*)d_in[5];
    const float* b_l0b   = (const float*)d_in[6];
    const float* wih_l1f = (const float*)d_in[7];
    const float* whh_l1f = (const float*)d_in[8];
    const float* b_l1f   = (const float*)d_in[9];
    const float* wih_l1b = (const float*)d_in[10];
    const float* whh_l1b = (const float*)d_in[11];
    const float* b_l1b   = (const float*)d_in[12];
    const float* fc1w    = (const float*)d_in[13];
    const float* fc1b    = (const float*)d_in[14];
    const float* bng     = (const float*)d_in[15];
    const float* bnb     = (const float*)d_in[16];
    const float* fc2w    = (const float*)d_in[17];
    const float* fc2b    = (const float*)d_in[18];
    const float* fc3w    = (const float*)d_in[19];
    const float* fc3b    = (const float*)d_in[20];
    const float* fc4w    = (const float*)d_in[21];
    const float* fc4b    = (const float*)d_in[22];

    // ---- workspace layout ----
    char* ws = (char*)d_ws;
    float* stats  = (float*)ws;                        // 512 B
    bf16*  fc1wb  = (bf16*)(ws + 4096);                // 102400 B
    bf16*  hs0    = (bf16*)(ws + 131072);              // 32 MiB
    bf16*  hs1    = (bf16*)(ws + 33685504);            // 32 MiB
    float* xg     = (float*)(ws + 67239936);           // 128 MiB (one chunk)
    bf16*  wb0f   = (bf16*)(ws + 201457664);           // 256 KiB
    bf16*  wb0b   = (bf16*)(ws + 201719808);           // 256 KiB
    bf16*  wb1f   = (bf16*)(ws + 201981952);           // 1 MiB
    bf16*  wb1b   = (bf16*)(ws + 203030528);           // 1 MiB
    bf16*  Wp0f   = (bf16*)(ws + 204079104);           // 512 KiB
    bf16*  Wp0b   = (bf16*)(ws + 204603392);           // 512 KiB
    bf16*  Wp1f   = (bf16*)(ws + 205127680);           // 512 KiB
    bf16*  Wp1b   = (bf16*)(ws + 205651968);           // 512 KiB
    float* cst    = (float*)(ws + 206176256);          // 256 KiB
    // post-rec overlays (xg / weight packs dead by then):
    bf16*  ctx    = (bf16*)(ws + 67239936);            // 32 MiB
    float* S      = (float*)(ws + 100794368);          // 64 MiB
    bf16*  P      = (bf16*)(ws + 167903232);           // 32 MiB
    float* fc1out = (float*)(ws + 201457664);          // 6.25 MiB
    bf16*  hs1T   = (bf16*)S;

    // ---- weight prep ----
    f2b_kernel<<<200, 256, 0, stream>>>(fc1w, fc1wb, 51200);
    f2b_kernel<<<512, 256, 0, stream>>>(wih_l0f, wb0f, 131072);
    f2b_kernel<<<512, 256, 0, stream>>>(wih_l0b, wb0b, 131072);
    f2b_kernel<<<2048, 256, 0, stream>>>(wih_l1f, wb1f, 524288);
    f2b_kernel<<<2048, 256, 0, stream>>>(wih_l1b, wb1b, 524288);
    pack_whh<<<128, 256, 0, stream>>>(whh_l0f, Wp0f);
    pack_whh<<<128, 256, 0, stream>>>(whh_l0b, Wp0b);
    pack_whh<<<128, 256, 0, stream>>>(whh_l1f, Wp1f);
    pack_whh<<<128, 256, 0, stream>>>(whh_l1b, Wp1b);

    constexpr int REC_LDS = 131072 + 2*2176;   // 135,424 B
    hipFuncSetAttribute(reinterpret_cast<const void*>(&rec_kernel),
                        hipFuncAttributeMaxDynamicSharedMemorySize, REC_LDS);

    dim3 gxg(256, 16, 2);
    // ---- layer 0 ----
    xg_gemm<128, true><<<gxg, 256, 0, stream>>>(x, wb0f, wb0b, b_l0f, b_l0b, xg, 0);
    rec_kernel<<<32, 512, REC_LDS, stream>>>(xg, Wp0f, Wp0b, hs0, cst, 0);
    xg_gemm<128, true><<<gxg, 256, 0, stream>>>(x, wb0f, wb0b, b_l0f, b_l0b, xg, 1);
    rec_kernel<<<32, 512, REC_LDS, stream>>>(xg, Wp0f, Wp0b, hs0, cst, 1);
    // ---- layer 1 ----
    xg_gemm<512, false><<<gxg, 256, 0, stream>>>(hs0, wb1f, wb1b, b_l1f, b_l1b, xg, 0);
    rec_kernel<<<32, 512, REC_LDS, stream>>>(xg, Wp1f, Wp1b, hs1, cst, 0);
    xg_gemm<512, false><<<gxg, 256, 0, stream>>>(hs0, wb1f, wb1b, b_l1f, b_l1b, xg, 1);
    rec_kernel<<<32, 512, REC_LDS, stream>>>(xg, Wp1f, Wp1b, hs1, cst, 1);

    // ---- attention + head ----
    dim3 g88(8, 8, 64);
    sgemm_scores<<<g88, 256, 0, stream>>>(hs1, S);
    softmax_rows<<<8192, 256, 0, stream>>>(S, P);
    transpose_nt<<<g88, 256, 0, stream>>>(hs1, hs1T);
    ctx_gemm<<<g88, 256, 0, stream>>>(P, hs1T, ctx);
    fc1_gemm<<<512, 256, 0, stream>>>(ctx, hs1, fc1wb, fc1b, fc1out);
    bn_stats<<<50, 256, 0, stream>>>(fc1out, stats);
    tail_kernel<<<128, 256, 0, stream>>>(fc1out, stats, bng, bnb, fc2w, fc2b,
                                         fc3w, fc3b, fc4w, fc4b, (float*)d_out);
    (void)in_sizes; (void)n_in; (void)out_size; (void)ws_size;
}

// Round 6
// 3263.757 us; speedup vs baseline: 1.5685x; 1.5685x over previous
//
#include <hip/hip_runtime.h>
#include <hip/hip_bf16.h>

typedef __bf16 bf16;
typedef __bf16 bf16x8 __attribute__((ext_vector_type(8)));
typedef float floatx4 __attribute__((ext_vector_type(4)));
typedef float floatx16 __attribute__((ext_vector_type(16)));

#define TSEQ 512
#define MFMA16 __builtin_amdgcn_mfma_f32_16x16x32_bf16

__device__ __forceinline__ float sigm(float x){ return 1.0f/(1.0f + __expf(-x)); }
__device__ __forceinline__ float tanh_fast(float x){
    float e = __expf(2.0f*x);
    return 1.0f - 2.0f/(e + 1.0f);   // correct limits at +-inf
}

// fp32 -> bf16 converter
__global__ __launch_bounds__(256, 4)
void f2b_kernel(const float* __restrict__ in, bf16* __restrict__ out, int n)
{
    int i = blockIdx.x*256 + threadIdx.x;
    if (i < n) out[i] = (bf16)in[i];
}

// ---------------------------------------------------------------------------
// Pack Whh (1024 x 256 fp32) into MFMA-16x16x32 B-frag-major bf16 layout:
// Wp[ntile 0..63][kstep 0..7][lane 0..63][e 0..7], value =
//   Whh[gatecol = ntile*16 + (lane&15)][k = kstep*32 + (lane>>4)*8 + e]
// ---------------------------------------------------------------------------
__global__ __launch_bounds__(256, 4)
void pack_whh(const float* __restrict__ whh, bf16* __restrict__ wp)
{
    int idx = blockIdx.x*256 + threadIdx.x;
    if (idx >= 32768) return;
    int lane = idx & 63, ks = (idx >> 6) & 7, nt = idx >> 9;
    int row = nt*16 + (lane & 15);
    int k0  = ks*32 + (lane >> 4)*8;
    const float* src = whh + (size_t)row*256 + k0;
    bf16x8 v;
    #pragma unroll
    for (int e = 0; e < 8; e++) v[e] = (bf16)src[e];
    ((bf16x8*)wp)[idx] = v;
}

// ---------------------------------------------------------------------------
// xg = x @ Wih^T + bias for one 256-step chunk, both dirs (blockIdx.z).
// Plane layout (16 KiB per (rec-block, sloc)):
//   xg[(d*16+bg)*256 + sloc][w 0..7][j 0..7][l15 0..15][r 0..3] fp32
// A-tile = 64 rows = (16 slocs x 4 seqs, r-fast): row = slot*4 + r.
// Epilogue: each thread writes 4 coalesced float4 (consecutive r).
// Grid (256,16,2): bx = bg*16 + sg, by = coltile, bz = dir.
// ---------------------------------------------------------------------------
template<int DIN, bool XF32>
__global__ __launch_bounds__(256, 2)
void xg_gemm(const void* __restrict__ xin,
             const bf16* __restrict__ wbf, const bf16* __restrict__ wbb,
             const float* __restrict__ bf_, const float* __restrict__ bb_,
             float* __restrict__ xg, int chunk)
{
    __shared__ char smem[64*144*2];
    const int tid = threadIdx.x;
    const int wv = tid >> 6, ln = tid & 63;
    const int mi = wv & 1, ni = wv >> 1;
    const int l31 = ln & 31, lh = ln >> 5;
    char* At = smem;
    char* Bt = smem + 64*144;

    const int d   = blockIdx.z;
    const int bg  = blockIdx.x >> 4;        // seq group (4 seqs)
    const int sg  = blockIdx.x & 15;        // sloc group (16 slocs)
    const int n0  = blockIdx.y * 64;
    const bf16*  wb   = d ? wbb : wbf;
    const float* bias = d ? bb_ : bf_;
    const int seq0  = bg*4;
    const int tbase = d ? (511 - (chunk*256 + sg*16)) : (chunk*256 + sg*16);
    const int stp   = d ? -1 : 1;

    floatx16 acc;
    #pragma unroll
    for (int r = 0; r < 16; r++) acc[r] = 0.0f;

    for (int kc = 0; kc < DIN; kc += 64) {
        __syncthreads();
        for (int c = tid; c < 1024; c += 256) {
            const int which = c >> 9, idx = c & 511;
            const int row = idx >> 3, k8 = idx & 7;
            if (which == 0) {
                const int trow = tbase + (row >> 2)*stp;
                const int seq  = seq0 + (row & 3);
                if constexpr (XF32) {
                    const float* src = (const float*)xin
                        + ((size_t)seq*TSEQ + trow)*DIN + kc + k8*8;
                    const float4 lo = *(const float4*)src;
                    const float4 hi = *(const float4*)(src+4);
                    bf16 tmp[8] = {(bf16)lo.x,(bf16)lo.y,(bf16)lo.z,(bf16)lo.w,
                                   (bf16)hi.x,(bf16)hi.y,(bf16)hi.z,(bf16)hi.w};
                    *(uint4*)(At + row*144 + k8*16) = *(uint4*)tmp;
                } else {
                    const bf16* src = (const bf16*)xin
                        + ((size_t)seq*TSEQ + trow)*DIN + kc + k8*8;
                    *(uint4*)(At + row*144 + k8*16) = *(const uint4*)src;
                }
            } else {
                *(uint4*)(Bt + row*144 + k8*16) =
                    *(const uint4*)(wb + (size_t)(n0+row)*DIN + kc + k8*8);
            }
        }
        __syncthreads();
        #pragma unroll
        for (int ks = 0; ks < 4; ks++) {
            bf16x8 a = *(const bf16x8*)(At + (mi*32 + l31)*144 + ks*32 + lh*16);
            bf16x8 b = *(const bf16x8*)(Bt + (ni*32 + l31)*144 + ks*32 + lh*16);
            acc = __builtin_amdgcn_mfma_f32_32x32x16_bf16(a, b, acc, 0, 0, 0);
        }
    }
    const int col = n0 + ni*32 + l31;
    const int nt = col >> 4, l15c = col & 15;
    const int wq = nt & 7, jq = nt >> 3;
    const float bv = bias[col];
    char* pb = (char*)xg + ((size_t)((d*16 + bg)*256 + sg*16))*16384
             + (size_t)(((wq*8 + jq)*16 + l15c)*16);
    #pragma unroll
    for (int g = 0; g < 4; g++) {
        const int slotL = mi*8 + 2*g + lh;   // sloc offset within group
        float4 v = make_float4(acc[4*g+0]+bv, acc[4*g+1]+bv,
                               acc[4*g+2]+bv, acc[4*g+3]+bv);
        *(float4*)(pb + (size_t)slotL*16384) = v;
    }
}

// ---------------------------------------------------------------------------
// Batch-split recurrence v6. 32 blocks = 2 dir x 16 groups of 4 seqs; 512 thr
// (8 waves, 2/SIMD). Zero inter-block traffic.
// Weight tiers per wave (ntile = j*8+w):  j=0..4 reg (160 VGPR),
//   j=5,6 LDS-resident (16 ntiles, 128 KiB), j=7 streamed from L2 (SB).
// xg path (the round-5 fix): LDS ring slot (16 KiB). Per step: C-in via 8
// broadcast ds_read_b128 from own wave slice; NEXT plane loaded to regs at
// step TOP (T14 issue-early) and ds_written at step BOTTOM (write-late) ->
// ~0.7 step of latency cover, and the barrier's vmcnt drain becomes free.
// Gate g of cell (seq r, hcol=(jj*8+w)*16+l15), jj=lq>>1, = acc[2g+jj][r].
// ---------------------------------------------------------------------------
__global__ __launch_bounds__(512, 1)
void rec_kernel(const float* __restrict__ xg,
                const bf16* __restrict__ WpF, const bf16* __restrict__ WpB,
                bf16* __restrict__ hsout, float* __restrict__ cst, int chunk)
{
    extern __shared__ char smem[];
    bf16x8* Wlds = (bf16x8*)smem;            // ntiles 40..55: 128 KiB
    char* ring = smem + 131072;              // xg plane slot: 16 KiB
    char* hb0  = smem + 147456;              // 4 rows x 544 B
    char* hb1  = hb0 + 2176;

    const int tid = threadIdx.x;
    const int w = tid >> 6, l = tid & 63;
    const int l15 = l & 15, lq = l >> 4;
    const int blk = blockIdx.x;
    const int d = blk >> 4, bg = blk & 15;
    const bf16x8* Wp = (const bf16x8*)(d ? WpB : WpF);

    // LDS weight tier: ntiles 40..55 (j=5,6 for all waves)
    for (int i = tid; i < 8192; i += 512) Wlds[i] = Wp[40*512 + i];

    // reg tier j=0..4 (nt = j*8+w)
    bf16x8 WR[5][8];
    #pragma unroll
    for (int j = 0; j < 5; j++)
        #pragma unroll
        for (int ks = 0; ks < 8; ks++)
            WR[j][ks] = Wp[((j*8 + w)*8 + ks)*64 + l];
    // streamed tier j=7 (nt = 56+w)
    const int sbBase = ((56 + w)*8)*64 + l;
    bf16x8 SB[8];
    #pragma unroll
    for (int ks = 0; ks < 8; ks++) SB[ks] = Wp[sbBase + ks*64];

    // h buffer init (sl=0 reads hb0)
    if (chunk == 0) {
        if (tid < 272) ((uint4*)hb0)[tid] = make_uint4(0,0,0,0); // hb0+hb1
    } else if (tid < 128) {
        const int tprev = d ? (512 - chunk*256) : (chunk*256 - 1);
        const int row = tid >> 5, c8 = (tid & 31)*8;
        uint4 v = *(const uint4*)(hsout
            + ((size_t)(bg*4 + row)*TSEQ + tprev)*512 + d*256 + c8);
        *(uint4*)(hb0 + row*544 + c8*2) = v;
    }

    // c-state: 4 cells (seq r=0..3, col hcol); dup x2 across lq&1
    float cs[4];
    if (chunk == 0) { cs[0]=cs[1]=cs[2]=cs[3]=0.0f; }
    else {
        float4 cv = ((const float4*)cst)[blk*512 + tid];
        cs[0]=cv.x; cs[1]=cv.y; cs[2]=cv.z; cs[3]=cv.w;
    }

    const char* xgp = (const char*)xg + ((size_t)blk*256)*16384;

    // prologue: fill ring with plane sl=0 (each wave its own 2 KiB slice)
    {
        const char* pn = xgp + (size_t)w*2048;
        uint4 s0 = *(const uint4*)(pn + l*16);
        uint4 s1 = *(const uint4*)(pn + 1024 + l*16);
        *(uint4*)(ring + w*2048 + l*16) = s0;
        *(uint4*)(ring + w*2048 + 1024 + l*16) = s1;
    }
    __syncthreads();

    const int aoff = (l15 & 3)*544 + lq*16;
    const int i5b = w*512 + l;               // Wlds idx j=5 (+ks*64)
    const int i6b = (8 + w)*512 + l;         // j=6
    const bool hi2 = (lq >= 2);
    const int hcol = ((hi2 ? 8 : 0) + w)*16 + l15;
    const size_t hgbase = (size_t)(bg*4)*TSEQ*512 + d*256 + hcol;
    const int rslice = w*2048;

    for (int sl = 0; sl < 256; ++sl) {
        const int s = chunk*256 + sl;
        const int t = d ? (511 - s) : s;
        const char* hr = (sl & 1) ? hb1 : hb0;
        char* hw = (sl & 1) ? hb0 : hb1;

        // ---- C-in from ring (8 broadcast ds_read_b128, own wave slice) ----
        floatx4 acc[8];
        #pragma unroll
        for (int j = 0; j < 8; j++)
            acc[j] = *(const floatx4*)(ring + rslice + (j*16 + l15)*16);

        // ---- issue-early: next plane global loads (consumed at bottom) ----
        uint4 stg0, stg1;
        if (sl < 255) {
            const char* pn = xgp + (size_t)(sl + 1)*16384 + rslice;
            stg0 = *(const uint4*)(pn + l*16);
            stg1 = *(const uint4*)(pn + 1024 + l*16);
        }

        // ---- MFMA: gates = xg + h_prev @ Whh^T ----
        #pragma unroll
        for (int ks = 0; ks < 8; ks++) {
            bf16x8 A = *(const bf16x8*)(hr + aoff + ks*64);
            acc[0] = MFMA16(A, WR[0][ks], acc[0], 0,0,0);
            acc[1] = MFMA16(A, WR[1][ks], acc[1], 0,0,0);
            acc[2] = MFMA16(A, WR[2][ks], acc[2], 0,0,0);
            acc[3] = MFMA16(A, WR[3][ks], acc[3], 0,0,0);
            acc[4] = MFMA16(A, WR[4][ks], acc[4], 0,0,0);
            acc[5] = MFMA16(A, Wlds[i5b + ks*64], acc[5], 0,0,0);
            acc[6] = MFMA16(A, Wlds[i6b + ks*64], acc[6], 0,0,0);
            acc[7] = MFMA16(A, SB[ks], acc[7], 0,0,0);
        }
        // refill streamed tier for next step (full-step distance)
        if (sl < 255) {
            int zx;
            asm volatile("s_mov_b32 %0, 0" : "=s"(zx));  // defeat LICM
            #pragma unroll
            for (int ks = 0; ks < 8; ks++) SB[ks] = Wp[sbBase + ks*64 + zx];
        }

        // ---- gate extraction (cndmask on lq-half) + cell math ----
        float hv[4];
        #pragma unroll
        for (int r = 0; r < 4; r++) {
            const float gI = hi2 ? acc[1][r] : acc[0][r];
            const float gF = hi2 ? acc[3][r] : acc[2][r];
            const float gG = hi2 ? acc[5][r] : acc[4][r];
            const float gO = hi2 ? acc[7][r] : acc[6][r];
            const float cn = sigm(gF)*cs[r] + sigm(gI)*tanh_fast(gG);
            cs[r] = cn;
            hv[r] = sigm(gO)*tanh_fast(cn);
        }

        // ---- write-late: ring <- staged next plane ----
        if (sl < 255) {
            *(uint4*)(ring + rslice + l*16) = stg0;
            *(uint4*)(ring + rslice + 1024 + l*16) = stg1;
        }

        // ---- h stores: LDS (next step A) + global (uniform, dup x2) ----
        #pragma unroll
        for (int r = 0; r < 4; r++)
            *(bf16*)(hw + r*544 + hcol*2) = (bf16)hv[r];
        bf16* hgp = hsout + hgbase + (size_t)t*512;
        #pragma unroll
        for (int r = 0; r < 4; r++)
            hgp[(size_t)r*TSEQ*512] = (bf16)hv[r];

        __syncthreads();
    }

    ((float4*)cst)[blk*512 + tid] = make_float4(cs[0], cs[1], cs[2], cs[3]);
}

// ---------------------------------------------------------------------------
// Shared 64x64 bf16 GEMM main loop (attention chain) — unchanged.
// ---------------------------------------------------------------------------
__device__ __forceinline__ floatx16 gemm_loop(const bf16* __restrict__ A0,
                                              const bf16* __restrict__ Bt0,
                                              int lda, int ldb, int K, int brows,
                                              char* smem)
{
    const int tid = threadIdx.x;
    const int wave = tid >> 6, lane = tid & 63;
    const int mi = wave & 1, ni = wave >> 1;
    const int l31 = lane & 31, lh = lane >> 5;
    char* At = smem;
    char* Bt = smem + 64*144;
    floatx16 acc;
    #pragma unroll
    for (int r = 0; r < 16; r++) acc[r] = 0.0f;

    for (int kc = 0; kc < K; kc += 64) {
        __syncthreads();
        for (int c = tid; c < 1024; c += 256) {
            int which = c >> 9;
            int idx = c & 511;
            int row = idx >> 3, kch = idx & 7;
            uint4 v;
            if (which == 0) {
                v = *(const uint4*)(A0 + (size_t)row*lda + kc + kch*8);
                *(uint4*)(At + row*144 + kch*16) = v;
            } else {
                if (row < brows) v = *(const uint4*)(Bt0 + (size_t)row*ldb + kc + kch*8);
                else             v = make_uint4(0,0,0,0);
                *(uint4*)(Bt + row*144 + kch*16) = v;
            }
        }
        __syncthreads();
        #pragma unroll
        for (int ks = 0; ks < 4; ks++) {
            bf16x8 a = *(const bf16x8*)(At + (mi*32 + l31)*144 + ks*32 + lh*16);
            bf16x8 b = *(const bf16x8*)(Bt + (ni*32 + l31)*144 + ks*32 + lh*16);
            acc = __builtin_amdgcn_mfma_f32_32x32x16_bf16(a, b, acc, 0, 0, 0);
        }
    }
    return acc;
}

__global__ __launch_bounds__(256, 2)
void sgemm_scores(const bf16* __restrict__ hs1, float* __restrict__ S)
{
    __shared__ char smem[64*144*2];
    int n = blockIdx.z, tm = blockIdx.x, tn = blockIdx.y;
    const bf16* base = hs1 + (size_t)n*512*512;
    floatx16 acc = gemm_loop(base + (size_t)tm*64*512, base + (size_t)tn*64*512,
                             512, 512, 512, 64, smem);
    int wave = threadIdx.x >> 6, lane = threadIdx.x & 63;
    int mi = wave & 1, ni = wave >> 1;
    #pragma unroll
    for (int r = 0; r < 16; r++) {
        int row = tm*64 + mi*32 + (r&3) + 8*(r>>2) + 4*(lane>>5);
        int col = tn*64 + ni*32 + (lane&31);
        S[(size_t)n*512*512 + (size_t)row*512 + col] = acc[r];
    }
}

__global__ __launch_bounds__(256, 4)
void softmax_rows(const float* __restrict__ S, bf16* __restrict__ P)
{
    int row = blockIdx.x*4 + (threadIdx.x >> 6);
    int lane = threadIdx.x & 63;
    const float* src = S + (size_t)row*512 + lane*8;
    float4 a = *(const float4*)(src);
    float4 b = *(const float4*)(src + 4);
    float v[8] = {a.x,a.y,a.z,a.w,b.x,b.y,b.z,b.w};
    float m = v[0];
    #pragma unroll
    for (int j = 1; j < 8; j++) m = fmaxf(m, v[j]);
    #pragma unroll
    for (int off = 32; off > 0; off >>= 1) m = fmaxf(m, __shfl_xor(m, off));
    float s = 0.0f;
    #pragma unroll
    for (int j = 0; j < 8; j++) { v[j] = __expf(v[j]-m); s += v[j]; }
    #pragma unroll
    for (int off = 32; off > 0; off >>= 1) s += __shfl_xor(s, off);
    float inv = 1.0f/s;
    union { uint4 u; bf16 h[8]; } pk;
    #pragma unroll
    for (int j = 0; j < 8; j++) pk.h[j] = (bf16)(v[j]*inv);
    *(uint4*)(P + (size_t)row*512 + lane*8) = pk.u;
}

__global__ __launch_bounds__(256, 2)
void transpose_nt(const bf16* __restrict__ hs1, bf16* __restrict__ hs1T)
{
    __shared__ bf16 tile[64][72];
    int n = blockIdx.z, tX = blockIdx.x, fX = blockIdx.y;
    const bf16* src = hs1 + (size_t)n*512*512;
    for (int c = threadIdx.x; c < 512; c += 256) {
        int row = c >> 3, kch = c & 7;
        *(uint4*)(&tile[row][kch*8]) =
            *(const uint4*)(src + (size_t)(tX*64+row)*512 + fX*64 + kch*8);
    }
    __syncthreads();
    bf16* dst = hs1T + (size_t)n*512*512;
    for (int c = threadIdx.x; c < 512; c += 256) {
        int frow = c >> 3, tch = c & 7;
        bf16 tmp[8];
        #pragma unroll
        for (int j = 0; j < 8; j++) tmp[j] = tile[tch*8+j][frow];
        *(uint4*)(dst + (size_t)(fX*64+frow)*512 + tX*64 + tch*8) = *(uint4*)tmp;
    }
}

__global__ __launch_bounds__(256, 2)
void ctx_gemm(const bf16* __restrict__ P, const bf16* __restrict__ hs1T,
              bf16* __restrict__ ctx)
{
    __shared__ char smem[64*144*2];
    int n = blockIdx.z, tm = blockIdx.x, tn = blockIdx.y;
    const bf16* A0 = P    + (size_t)n*512*512 + (size_t)tm*64*512;
    const bf16* B0 = hs1T + (size_t)n*512*512 + (size_t)tn*64*512;
    floatx16 acc = gemm_loop(A0, B0, 512, 512, 512, 64, smem);
    int wave = threadIdx.x >> 6, lane = threadIdx.x & 63;
    int mi = wave & 1, ni = wave >> 1;
    #pragma unroll
    for (int r = 0; r < 16; r++) {
        int row = tm*64 + mi*32 + (r&3) + 8*(r>>2) + 4*(lane>>5);
        int col = tn*64 + ni*32 + (lane&31);
        ctx[((size_t)n*512 + row)*512 + col] = (bf16)acc[r];
    }
}

__global__ __launch_bounds__(256, 2)
void fc1_gemm(const bf16* __restrict__ ctx, const bf16* __restrict__ hs1,
              const bf16* __restrict__ wb, const float* __restrict__ b,
              float* __restrict__ outp)
{
    __shared__ char smem[64*144*2];
    const int tid = threadIdx.x;
    const int wave = tid >> 6, lane = tid & 63;
    const int mi = wave & 1, ni = wave >> 1;
    const int l31 = lane & 31, lh = lane >> 5;
    char* At = smem;
    char* Bt = smem + 64*144;
    const int m0 = blockIdx.x*64;
    floatx16 acc;
    #pragma unroll
    for (int r = 0; r < 16; r++) acc[r] = 0.0f;

    for (int kc = 0; kc < 1024; kc += 64) {
        const bf16* Asrc = (kc < 512) ? ctx : hs1;
        const int koff = kc & 511;
        __syncthreads();
        for (int c = tid; c < 1024; c += 256) {
            int which = c >> 9, idx = c & 511;
            int row = idx >> 3, kch = idx & 7;
            uint4 v;
            if (which == 0) {
                v = *(const uint4*)(Asrc + (size_t)(m0+row)*512 + koff + kch*8);
                *(uint4*)(At + row*144 + kch*16) = v;
            } else {
                if (row < 50) v = *(const uint4*)(wb + (size_t)row*1024 + kc + kch*8);
                else          v = make_uint4(0,0,0,0);
                *(uint4*)(Bt + row*144 + kch*16) = v;
            }
        }
        __syncthreads();
        #pragma unroll
        for (int ks = 0; ks < 4; ks++) {
            bf16x8 a = *(const bf16x8*)(At + (mi*32 + l31)*144 + ks*32 + lh*16);
            bf16x8 bb = *(const bf16x8*)(Bt + (ni*32 + l31)*144 + ks*32 + lh*16);
            acc = __builtin_amdgcn_mfma_f32_32x32x16_bf16(a, bb, acc, 0, 0, 0);
        }
    }
    #pragma unroll
    for (int r = 0; r < 16; r++) {
        int row = m0 + mi*32 + (r&3) + 8*(r>>2) + 4*lh;
        int col = ni*32 + l31;
        if (col < 50) {
            float v = acc[r] + b[col];
            outp[(size_t)row*50 + col] = fmaxf(v, 0.0f);
        }
    }
}

__global__ __launch_bounds__(256, 4)
void bn_stats(const float* __restrict__ fc1out, float* __restrict__ stats)
{
    __shared__ float sh[512];
    int c = blockIdx.x;
    float s = 0.0f, ss = 0.0f;
    for (int i = threadIdx.x; i < 32768; i += 256) {
        int n = i >> 9, q = i & 511;
        float x = fc1out[(size_t)n*25600 + c*512 + q];
        s += x; ss += x*x;
    }
    sh[threadIdx.x] = s; sh[256 + threadIdx.x] = ss;
    __syncthreads();
    for (int o = 128; o > 0; o >>= 1) {
        if (threadIdx.x < o) {
            sh[threadIdx.x] += sh[threadIdx.x + o];
            sh[256+threadIdx.x] += sh[256+threadIdx.x + o];
        }
        __syncthreads();
    }
    if (threadIdx.x == 0) {
        float mean = sh[0] / 32768.0f;
        float var  = sh[256] / 32768.0f - mean*mean;
        stats[c]      = mean;
        stats[64 + c] = rsqrtf(var + 1e-5f);
    }
}

__global__ __launch_bounds__(256, 4)
void tail_kernel(const float* __restrict__ fc1out, const float* __restrict__ stats,
                 const float* __restrict__ bng, const float* __restrict__ bnb,
                 const float* __restrict__ fc2w, const float* __restrict__ fc2b,
                 const float* __restrict__ fc3w, const float* __restrict__ fc3b,
                 const float* __restrict__ fc4w, const float* __restrict__ fc4b,
                 float* __restrict__ outp)
{
    __shared__ float W2[1250], W3[250], B2[25], B3[10], W4[20], B4[2];
    __shared__ float G[50], Bb[50], MU[50], IS[50];
    for (int i = threadIdx.x; i < 1250; i += 256) W2[i] = fc2w[i];
    for (int i = threadIdx.x; i < 250;  i += 256) W3[i] = fc3w[i];
    if (threadIdx.x < 25) B2[threadIdx.x] = fc2b[threadIdx.x];
    if (threadIdx.x < 20) W4[threadIdx.x] = fc4w[threadIdx.x];
    if (threadIdx.x < 10) B3[threadIdx.x] = fc3b[threadIdx.x];
    if (threadIdx.x < 2)  B4[threadIdx.x] = fc4b[threadIdx.x];
    if (threadIdx.x < 50) {
        G[threadIdx.x]  = bng[threadIdx.x];
        Bb[threadIdx.x] = bnb[threadIdx.x];
        MU[threadIdx.x] = stats[threadIdx.x];
        IS[threadIdx.x] = stats[64 + threadIdx.x];
    }
    __syncthreads();
    int m = blockIdx.x*256 + threadIdx.x;
    int t = m & 511;
    const float* src = fc1out + (size_t)m*50;
    float x[50];
    #pragma unroll
    for (int c = 0; c < 50; c++) {
        int j = (t*50 + c) >> 9;
        x[c] = (src[c] - MU[j])*IS[j]*G[j] + Bb[j];
    }
    float y2[25];
    #pragma unroll
    for (int o = 0; o < 25; o++) {
        float a = B2[o];
        for (int c = 0; c < 50; c++) a += x[c]*W2[o*50+c];
        y2[o] = fmaxf(a, 0.0f);
    }
    float y3[10];
    #pragma unroll
    for (int o = 0; o < 10; o++) {
        float a = B3[o];
        for (int c = 0; c < 25; c++) a += y2[c]*W3[o*25+c];
        y3[o] = fmaxf(a, 0.0f);
    }
    #pragma unroll
    for (int o = 0; o < 2; o++) {
        float a = B4[o];
        for (int c = 0; c < 10; c++) a += y3[c]*W4[o*10+c];
        outp[(size_t)m*2 + o] = a;
    }
}

extern "C" void kernel_launch(void* const* d_in, const int* in_sizes, int n_in,
                              void* d_out, int out_size, void* d_ws, size_t ws_size,
                              hipStream_t stream)
{
    const float* x       = (const float*)d_in[0];
    const float* wih_l0f = (const float*)d_in[1];
    const float* whh_l0f = (const float*)d_in[2];
    const float* b_l0f   = (const float*)d_in[3];
    const float* wih_l0b = (const float*)d_in[4];
    const float* whh_l0b = (const float*)d_in[5];
    const float* b_l0b   = (const float*)d_in[6];
    const float* wih_l1f = (const float*)d_in[7];
    const float* whh_l1f = (const float*)d_in[8];
    const float* b_l1f   = (const float*)d_in[9];
    const float* wih_l1b = (const float*)d_in[10];
    const float* whh_l1b = (const float*)d_in[11];
    const float* b_l1b   = (const float*)d_in[12];
    const float* fc1w    = (const float*)d_in[13];
    const float* fc1b    = (const float*)d_in[14];
    const float* bng     = (const float*)d_in[15];
    const float* bnb     = (const float*)d_in[16];
    const float* fc2w    = (const float*)d_in[17];
    const float* fc2b    = (const float*)d_in[18];
    const float* fc3w    = (const float*)d_in[19];
    const float* fc3b    = (const float*)d_in[20];
    const float* fc4w    = (const float*)d_in[21];
    const float* fc4b    = (const float*)d_in[22];

    // ---- workspace layout ----
    char* ws = (char*)d_ws;
    float* stats  = (float*)ws;                        // 512 B
    bf16*  fc1wb  = (bf16*)(ws + 4096);                // 102400 B
    bf16*  hs0    = (bf16*)(ws + 131072);              // 32 MiB
    bf16*  hs1    = (bf16*)(ws + 33685504);            // 32 MiB
    float* xg     = (float*)(ws + 67239936);           // 128 MiB (one chunk)
    bf16*  wb0f   = (bf16*)(ws + 201457664);           // 256 KiB
    bf16*  wb0b   = (bf16*)(ws + 201719808);           // 256 KiB
    bf16*  wb1f   = (bf16*)(ws + 201981952);           // 1 MiB
    bf16*  wb1b   = (bf16*)(ws + 203030528);           // 1 MiB
    bf16*  Wp0f   = (bf16*)(ws + 204079104);           // 512 KiB
    bf16*  Wp0b   = (bf16*)(ws + 204603392);           // 512 KiB
    bf16*  Wp1f   = (bf16*)(ws + 205127680);           // 512 KiB
    bf16*  Wp1b   = (bf16*)(ws + 205651968);           // 512 KiB
    float* cst    = (float*)(ws + 206176256);          // 256 KiB
    // post-rec overlays (xg / weight packs dead by then):
    bf16*  ctx    = (bf16*)(ws + 67239936);            // 32 MiB
    float* S      = (float*)(ws + 100794368);          // 64 MiB
    bf16*  P      = (bf16*)(ws + 167903232);           // 32 MiB
    float* fc1out = (float*)(ws + 201457664);          // 6.25 MiB
    bf16*  hs1T   = (bf16*)S;

    // ---- weight prep ----
    f2b_kernel<<<200, 256, 0, stream>>>(fc1w, fc1wb, 51200);
    f2b_kernel<<<512, 256, 0, stream>>>(wih_l0f, wb0f, 131072);
    f2b_kernel<<<512, 256, 0, stream>>>(wih_l0b, wb0b, 131072);
    f2b_kernel<<<2048, 256, 0, stream>>>(wih_l1f, wb1f, 524288);
    f2b_kernel<<<2048, 256, 0, stream>>>(wih_l1b, wb1b, 524288);
    pack_whh<<<128, 256, 0, stream>>>(whh_l0f, Wp0f);
    pack_whh<<<128, 256, 0, stream>>>(whh_l0b, Wp0b);
    pack_whh<<<128, 256, 0, stream>>>(whh_l1f, Wp1f);
    pack_whh<<<128, 256, 0, stream>>>(whh_l1b, Wp1b);

    constexpr int REC_LDS = 131072 + 16384 + 2*2176;   // 151,808 B
    hipFuncSetAttribute(reinterpret_cast<const void*>(&rec_kernel),
                        hipFuncAttributeMaxDynamicSharedMemorySize, REC_LDS);

    dim3 gxg(256, 16, 2);
    // ---- layer 0 ----
    xg_gemm<128, true><<<gxg, 256, 0, stream>>>(x, wb0f, wb0b, b_l0f, b_l0b, xg, 0);
    rec_kernel<<<32, 512, REC_LDS, stream>>>(xg, Wp0f, Wp0b, hs0, cst, 0);
    xg_gemm<128, true><<<gxg, 256, 0, stream>>>(x, wb0f, wb0b, b_l0f, b_l0b, xg, 1);
    rec_kernel<<<32, 512, REC_LDS, stream>>>(xg, Wp0f, Wp0b, hs0, cst, 1);
    // ---- layer 1 ----
    xg_gemm<512, false><<<gxg, 256, 0, stream>>>(hs0, wb1f, wb1b, b_l1f, b_l1b, xg, 0);
    rec_kernel<<<32, 512, REC_LDS, stream>>>(xg, Wp1f, Wp1b, hs1, cst, 0);
    xg_gemm<512, false><<<gxg, 256, 0, stream>>>(hs0, wb1f, wb1b, b_l1f, b_l1b, xg, 1);
    rec_kernel<<<32, 512, REC_LDS, stream>>>(xg, Wp1f, Wp1b, hs1, cst, 1);

    // ---- attention + head ----
    dim3 g88(8, 8, 64);
    sgemm_scores<<<g88, 256, 0, stream>>>(hs1, S);
    softmax_rows<<<8192, 256, 0, stream>>>(S, P);
    transpose_nt<<<g88, 256, 0, stream>>>(hs1, hs1T);
    ctx_gemm<<<g88, 256, 0, stream>>>(P, hs1T, ctx);
    fc1_gemm<<<512, 256, 0, stream>>>(ctx, hs1, fc1wb, fc1b, fc1out);
    bn_stats<<<50, 256, 0, stream>>>(fc1out, stats);
    tail_kernel<<<128, 256, 0, stream>>>(fc1out, stats, bng, bnb, fc2w, fc2b,
                                         fc3w, fc3b, fc4w, fc4b, (float*)d_out);
    (void)in_sizes; (void)n_in; (void)out_size; (void)ws_size;
}

// Round 7
// 3092.023 us; speedup vs baseline: 1.6556x; 1.0555x over previous
//
#include <hip/hip_runtime.h>
#include <hip/hip_bf16.h>

typedef __bf16 bf16;
typedef __bf16 bf16x8 __attribute__((ext_vector_type(8)));
typedef float floatx4 __attribute__((ext_vector_type(4)));
typedef float floatx16 __attribute__((ext_vector_type(16)));

#define TSEQ 512
#define MFMA16 __builtin_amdgcn_mfma_f32_16x16x32_bf16

__device__ __forceinline__ float sigm(float x){ return 1.0f/(1.0f + __expf(-x)); }
__device__ __forceinline__ float tanh_fast(float x){
    float e = __expf(2.0f*x);
    return 1.0f - 2.0f/(e + 1.0f);   // correct limits at +-inf
}

// fp32 -> bf16 converter
__global__ __launch_bounds__(256, 4)
void f2b_kernel(const float* __restrict__ in, bf16* __restrict__ out, int n)
{
    int i = blockIdx.x*256 + threadIdx.x;
    if (i < n) out[i] = (bf16)in[i];
}

// ---------------------------------------------------------------------------
// Pack Whh (1024 x 256 fp32) into MFMA-16x16x32 B-frag-major bf16 layout:
// Wp[ntile 0..63][kstep 0..7][lane 0..63][e 0..7], value =
//   Whh[gatecol = ntile*16 + (lane&15)][k = kstep*32 + (lane>>4)*8 + e]
// ---------------------------------------------------------------------------
__global__ __launch_bounds__(256, 4)
void pack_whh(const float* __restrict__ whh, bf16* __restrict__ wp)
{
    int idx = blockIdx.x*256 + threadIdx.x;
    if (idx >= 32768) return;
    int lane = idx & 63, ks = (idx >> 6) & 7, nt = idx >> 9;
    int row = nt*16 + (lane & 15);
    int k0  = ks*32 + (lane >> 4)*8;
    const float* src = whh + (size_t)row*256 + k0;
    bf16x8 v;
    #pragma unroll
    for (int e = 0; e < 8; e++) v[e] = (bf16)src[e];
    ((bf16x8*)wp)[idx] = v;
}

// ---------------------------------------------------------------------------
// xg = x @ Wih^T + bias for one 256-step chunk, both dirs (blockIdx.z).
// Plane layout (16 KiB per (rec-block, sloc)):
//   xg[(d*16+bg)*256 + sloc][w 0..7][j 0..7][l15 0..15][r 0..3] fp32
// A-tile = 64 rows = (16 slocs x 4 seqs, r-fast): row = slot*4 + r.
// Epilogue: each thread writes 4 coalesced float4 (consecutive r).
// Grid (256,16,2): bx = bg*16 + sg, by = coltile, bz = dir.
// ---------------------------------------------------------------------------
template<int DIN, bool XF32>
__global__ __launch_bounds__(256, 2)
void xg_gemm(const void* __restrict__ xin,
             const bf16* __restrict__ wbf, const bf16* __restrict__ wbb,
             const float* __restrict__ bf_, const float* __restrict__ bb_,
             float* __restrict__ xg, int chunk)
{
    __shared__ char smem[64*144*2];
    const int tid = threadIdx.x;
    const int wv = tid >> 6, ln = tid & 63;
    const int mi = wv & 1, ni = wv >> 1;
    const int l31 = ln & 31, lh = ln >> 5;
    char* At = smem;
    char* Bt = smem + 64*144;

    const int d   = blockIdx.z;
    const int bg  = blockIdx.x >> 4;        // seq group (4 seqs)
    const int sg  = blockIdx.x & 15;        // sloc group (16 slocs)
    const int n0  = blockIdx.y * 64;
    const bf16*  wb   = d ? wbb : wbf;
    const float* bias = d ? bb_ : bf_;
    const int seq0  = bg*4;
    const int tbase = d ? (511 - (chunk*256 + sg*16)) : (chunk*256 + sg*16);
    const int stp   = d ? -1 : 1;

    floatx16 acc;
    #pragma unroll
    for (int r = 0; r < 16; r++) acc[r] = 0.0f;

    for (int kc = 0; kc < DIN; kc += 64) {
        __syncthreads();
        for (int c = tid; c < 1024; c += 256) {
            const int which = c >> 9, idx = c & 511;
            const int row = idx >> 3, k8 = idx & 7;
            if (which == 0) {
                const int trow = tbase + (row >> 2)*stp;
                const int seq  = seq0 + (row & 3);
                if constexpr (XF32) {
                    const float* src = (const float*)xin
                        + ((size_t)seq*TSEQ + trow)*DIN + kc + k8*8;
                    const float4 lo = *(const float4*)src;
                    const float4 hi = *(const float4*)(src+4);
                    bf16 tmp[8] = {(bf16)lo.x,(bf16)lo.y,(bf16)lo.z,(bf16)lo.w,
                                   (bf16)hi.x,(bf16)hi.y,(bf16)hi.z,(bf16)hi.w};
                    *(uint4*)(At + row*144 + k8*16) = *(uint4*)tmp;
                } else {
                    const bf16* src = (const bf16*)xin
                        + ((size_t)seq*TSEQ + trow)*DIN + kc + k8*8;
                    *(uint4*)(At + row*144 + k8*16) = *(const uint4*)src;
                }
            } else {
                *(uint4*)(Bt + row*144 + k8*16) =
                    *(const uint4*)(wb + (size_t)(n0+row)*DIN + kc + k8*8);
            }
        }
        __syncthreads();
        #pragma unroll
        for (int ks = 0; ks < 4; ks++) {
            bf16x8 a = *(const bf16x8*)(At + (mi*32 + l31)*144 + ks*32 + lh*16);
            bf16x8 b = *(const bf16x8*)(Bt + (ni*32 + l31)*144 + ks*32 + lh*16);
            acc = __builtin_amdgcn_mfma_f32_32x32x16_bf16(a, b, acc, 0, 0, 0);
        }
    }
    const int col = n0 + ni*32 + l31;
    const int nt = col >> 4, l15c = col & 15;
    const int wq = nt & 7, jq = nt >> 3;
    const float bv = bias[col];
    char* pb = (char*)xg + ((size_t)((d*16 + bg)*256 + sg*16))*16384
             + (size_t)(((wq*8 + jq)*16 + l15c)*16);
    #pragma unroll
    for (int g = 0; g < 4; g++) {
        const int slotL = mi*8 + 2*g + lh;   // sloc offset within group
        float4 v = make_float4(acc[4*g+0]+bv, acc[4*g+1]+bv,
                               acc[4*g+2]+bv, acc[4*g+3]+bv);
        *(float4*)(pb + (size_t)slotL*16384) = v;
    }
}

// ---------------------------------------------------------------------------
// Batch-split recurrence v7. 32 blocks = 2 dir x 16 groups of 4 seqs; 512 thr
// (8 waves, 2/SIMD). Zero inter-block traffic.
// Weight tiers per wave (ntile = j*8+w):  j=0..4 reg (160 regs, AGPR),
//   j=5,6 LDS-resident (16 ntiles, 128 KiB), j=7 streamed from L2 (SB).
// xg path: LDS ring slot (16 KiB, wave-private slices). C-in via 8 broadcast
// ds_read_b128; NEXT plane loaded to regs at step TOP and ds_written at step
// BOTTOM (issue-early / write-late).
// v7 KEY CHANGE — light barrier: the only cross-wave data per step is the
// h double-buffer (LDS). Replace __syncthreads (which drains vmcnt(0) and
// stalls on SB/xg/hsout global ops nobody else needs) with
// `s_waitcnt lgkmcnt(0); s_barrier` — global ops float across steps (T4).
// h stores lane-split: even-lq -> LDS, odd-lq -> global (halves store instrs).
// ---------------------------------------------------------------------------
__global__ __launch_bounds__(512, 1)
void rec_kernel(const float* __restrict__ xg,
                const bf16* __restrict__ WpF, const bf16* __restrict__ WpB,
                bf16* __restrict__ hsout, float* __restrict__ cst, int chunk)
{
    extern __shared__ char smem[];
    bf16x8* Wlds = (bf16x8*)smem;            // ntiles 40..55: 128 KiB
    char* ring = smem + 131072;              // xg plane slot: 16 KiB
    char* hb0  = smem + 147456;              // 4 rows x 544 B
    char* hb1  = hb0 + 2176;

    const int tid = threadIdx.x;
    const int w = tid >> 6, l = tid & 63;
    const int l15 = l & 15, lq = l >> 4;
    const int blk = blockIdx.x;
    const int d = blk >> 4, bg = blk & 15;
    const bf16x8* Wp = (const bf16x8*)(d ? WpB : WpF);

    // LDS weight tier: ntiles 40..55 (j=5,6 for all waves)
    for (int i = tid; i < 8192; i += 512) Wlds[i] = Wp[40*512 + i];

    // reg tier j=0..4 (nt = j*8+w)
    bf16x8 WR[5][8];
    #pragma unroll
    for (int j = 0; j < 5; j++)
        #pragma unroll
        for (int ks = 0; ks < 8; ks++)
            WR[j][ks] = Wp[((j*8 + w)*8 + ks)*64 + l];
    // streamed tier j=7 (nt = 56+w)
    const int sbBase = ((56 + w)*8)*64 + l;
    bf16x8 SB[8];
    #pragma unroll
    for (int ks = 0; ks < 8; ks++) SB[ks] = Wp[sbBase + ks*64];

    // h buffer init (sl=0 reads hb0)
    if (chunk == 0) {
        if (tid < 272) ((uint4*)hb0)[tid] = make_uint4(0,0,0,0); // hb0+hb1
    } else if (tid < 128) {
        const int tprev = d ? (512 - chunk*256) : (chunk*256 - 1);
        const int row = tid >> 5, c8 = (tid & 31)*8;
        uint4 v = *(const uint4*)(hsout
            + ((size_t)(bg*4 + row)*TSEQ + tprev)*512 + d*256 + c8);
        *(uint4*)(hb0 + row*544 + c8*2) = v;
    }

    // c-state: 4 cells (seq r=0..3, col hcol); dup x2 across lq&1
    float cs[4];
    if (chunk == 0) { cs[0]=cs[1]=cs[2]=cs[3]=0.0f; }
    else {
        float4 cv = ((const float4*)cst)[blk*512 + tid];
        cs[0]=cv.x; cs[1]=cv.y; cs[2]=cv.z; cs[3]=cv.w;
    }

    const char* xgp = (const char*)xg + ((size_t)blk*256)*16384;

    // prologue: fill ring with plane sl=0 (each wave its own 2 KiB slice)
    {
        const char* pn = xgp + (size_t)w*2048;
        uint4 s0 = *(const uint4*)(pn + l*16);
        uint4 s1 = *(const uint4*)(pn + 1024 + l*16);
        *(uint4*)(ring + w*2048 + l*16) = s0;
        *(uint4*)(ring + w*2048 + 1024 + l*16) = s1;
    }
    __syncthreads();

    const int aoff = (l15 & 3)*544 + lq*16;
    const int i5b = w*512 + l;               // Wlds idx j=5 (+ks*64)
    const int i6b = (8 + w)*512 + l;         // j=6
    const bool hi2 = (lq >= 2);
    const int hcol = ((hi2 ? 8 : 0) + w)*16 + l15;
    const size_t hgbase = (size_t)(bg*4)*TSEQ*512 + d*256 + hcol;
    const int rslice = w*2048;

    for (int sl = 0; sl < 256; ++sl) {
        const int s = chunk*256 + sl;
        const int t = d ? (511 - s) : s;
        const char* hr = (sl & 1) ? hb1 : hb0;
        char* hw = (sl & 1) ? hb0 : hb1;

        // ---- C-in from ring (8 broadcast ds_read_b128, own wave slice) ----
        floatx4 acc[8];
        #pragma unroll
        for (int j = 0; j < 8; j++)
            acc[j] = *(const floatx4*)(ring + rslice + (j*16 + l15)*16);

        // ---- issue-early: next plane global loads (consumed at bottom) ----
        uint4 stg0, stg1;
        if (sl < 255) {
            const char* pn = xgp + (size_t)(sl + 1)*16384 + rslice;
            stg0 = *(const uint4*)(pn + l*16);
            stg1 = *(const uint4*)(pn + 1024 + l*16);
        }

        // ---- MFMA: gates = xg + h_prev @ Whh^T ----
        #pragma unroll
        for (int ks = 0; ks < 8; ks++) {
            bf16x8 A = *(const bf16x8*)(hr + aoff + ks*64);
            acc[0] = MFMA16(A, WR[0][ks], acc[0], 0,0,0);
            acc[1] = MFMA16(A, WR[1][ks], acc[1], 0,0,0);
            acc[2] = MFMA16(A, WR[2][ks], acc[2], 0,0,0);
            acc[3] = MFMA16(A, WR[3][ks], acc[3], 0,0,0);
            acc[4] = MFMA16(A, WR[4][ks], acc[4], 0,0,0);
            acc[5] = MFMA16(A, Wlds[i5b + ks*64], acc[5], 0,0,0);
            acc[6] = MFMA16(A, Wlds[i6b + ks*64], acc[6], 0,0,0);
            acc[7] = MFMA16(A, SB[ks], acc[7], 0,0,0);
        }
        // refill streamed tier for next step (full-step distance; floats
        // across the light barrier — no vmcnt drain anymore)
        if (sl < 255) {
            int zx;
            asm volatile("s_mov_b32 %0, 0" : "=s"(zx));  // defeat LICM
            #pragma unroll
            for (int ks = 0; ks < 8; ks++) SB[ks] = Wp[sbBase + ks*64 + zx];
        }

        // ---- gate extraction (cndmask on lq-half) + cell math ----
        float hv[4];
        #pragma unroll
        for (int r = 0; r < 4; r++) {
            const float gI = hi2 ? acc[1][r] : acc[0][r];
            const float gF = hi2 ? acc[3][r] : acc[2][r];
            const float gG = hi2 ? acc[5][r] : acc[4][r];
            const float gO = hi2 ? acc[7][r] : acc[6][r];
            const float cn = sigm(gF)*cs[r] + sigm(gI)*tanh_fast(gG);
            cs[r] = cn;
            hv[r] = sigm(gO)*tanh_fast(cn);
        }

        // ---- write-late: ring <- staged next plane (wave-private) ----
        if (sl < 255) {
            *(uint4*)(ring + rslice + l*16) = stg0;
            *(uint4*)(ring + rslice + 1024 + l*16) = stg1;
        }

        // ---- h stores, lane-split: even-lq -> LDS, odd-lq -> global ----
        if ((lq & 1) == 0) {
            #pragma unroll
            for (int r = 0; r < 4; r++)
                *(bf16*)(hw + r*544 + hcol*2) = (bf16)hv[r];
        } else {
            bf16* hgp = hsout + hgbase + (size_t)t*512;
            #pragma unroll
            for (int r = 0; r < 4; r++)
                hgp[(size_t)r*TSEQ*512] = (bf16)hv[r];
        }

        // ---- light barrier: order ONLY the LDS h-buffer hand-off ----
        __builtin_amdgcn_sched_barrier(0);
        asm volatile("s_waitcnt lgkmcnt(0)\n\ts_barrier" ::: "memory");
        __builtin_amdgcn_sched_barrier(0);
    }

    ((float4*)cst)[blk*512 + tid] = make_float4(cs[0], cs[1], cs[2], cs[3]);
}

// ---------------------------------------------------------------------------
// Shared 64x64 bf16 GEMM main loop (attention chain) — unchanged.
// ---------------------------------------------------------------------------
__device__ __forceinline__ floatx16 gemm_loop(const bf16* __restrict__ A0,
                                              const bf16* __restrict__ Bt0,
                                              int lda, int ldb, int K, int brows,
                                              char* smem)
{
    const int tid = threadIdx.x;
    const int wave = tid >> 6, lane = tid & 63;
    const int mi = wave & 1, ni = wave >> 1;
    const int l31 = lane & 31, lh = lane >> 5;
    char* At = smem;
    char* Bt = smem + 64*144;
    floatx16 acc;
    #pragma unroll
    for (int r = 0; r < 16; r++) acc[r] = 0.0f;

    for (int kc = 0; kc < K; kc += 64) {
        __syncthreads();
        for (int c = tid; c < 1024; c += 256) {
            int which = c >> 9;
            int idx = c & 511;
            int row = idx >> 3, kch = idx & 7;
            uint4 v;
            if (which == 0) {
                v = *(const uint4*)(A0 + (size_t)row*lda + kc + kch*8);
                *(uint4*)(At + row*144 + kch*16) = v;
            } else {
                if (row < brows) v = *(const uint4*)(Bt0 + (size_t)row*ldb + kc + kch*8);
                else             v = make_uint4(0,0,0,0);
                *(uint4*)(Bt + row*144 + kch*16) = v;
            }
        }
        __syncthreads();
        #pragma unroll
        for (int ks = 0; ks < 4; ks++) {
            bf16x8 a = *(const bf16x8*)(At + (mi*32 + l31)*144 + ks*32 + lh*16);
            bf16x8 b = *(const bf16x8*)(Bt + (ni*32 + l31)*144 + ks*32 + lh*16);
            acc = __builtin_amdgcn_mfma_f32_32x32x16_bf16(a, b, acc, 0, 0, 0);
        }
    }
    return acc;
}

__global__ __launch_bounds__(256, 2)
void sgemm_scores(const bf16* __restrict__ hs1, float* __restrict__ S)
{
    __shared__ char smem[64*144*2];
    int n = blockIdx.z, tm = blockIdx.x, tn = blockIdx.y;
    const bf16* base = hs1 + (size_t)n*512*512;
    floatx16 acc = gemm_loop(base + (size_t)tm*64*512, base + (size_t)tn*64*512,
                             512, 512, 512, 64, smem);
    int wave = threadIdx.x >> 6, lane = threadIdx.x & 63;
    int mi = wave & 1, ni = wave >> 1;
    #pragma unroll
    for (int r = 0; r < 16; r++) {
        int row = tm*64 + mi*32 + (r&3) + 8*(r>>2) + 4*(lane>>5);
        int col = tn*64 + ni*32 + (lane&31);
        S[(size_t)n*512*512 + (size_t)row*512 + col] = acc[r];
    }
}

__global__ __launch_bounds__(256, 4)
void softmax_rows(const float* __restrict__ S, bf16* __restrict__ P)
{
    int row = blockIdx.x*4 + (threadIdx.x >> 6);
    int lane = threadIdx.x & 63;
    const float* src = S + (size_t)row*512 + lane*8;
    float4 a = *(const float4*)(src);
    float4 b = *(const float4*)(src + 4);
    float v[8] = {a.x,a.y,a.z,a.w,b.x,b.y,b.z,b.w};
    float m = v[0];
    #pragma unroll
    for (int j = 1; j < 8; j++) m = fmaxf(m, v[j]);
    #pragma unroll
    for (int off = 32; off > 0; off >>= 1) m = fmaxf(m, __shfl_xor(m, off));
    float s = 0.0f;
    #pragma unroll
    for (int j = 0; j < 8; j++) { v[j] = __expf(v[j]-m); s += v[j]; }
    #pragma unroll
    for (int off = 32; off > 0; off >>= 1) s += __shfl_xor(s, off);
    float inv = 1.0f/s;
    union { uint4 u; bf16 h[8]; } pk;
    #pragma unroll
    for (int j = 0; j < 8; j++) pk.h[j] = (bf16)(v[j]*inv);
    *(uint4*)(P + (size_t)row*512 + lane*8) = pk.u;
}

__global__ __launch_bounds__(256, 2)
void transpose_nt(const bf16* __restrict__ hs1, bf16* __restrict__ hs1T)
{
    __shared__ bf16 tile[64][72];
    int n = blockIdx.z, tX = blockIdx.x, fX = blockIdx.y;
    const bf16* src = hs1 + (size_t)n*512*512;
    for (int c = threadIdx.x; c < 512; c += 256) {
        int row = c >> 3, kch = c & 7;
        *(uint4*)(&tile[row][kch*8]) =
            *(const uint4*)(src + (size_t)(tX*64+row)*512 + fX*64 + kch*8);
    }
    __syncthreads();
    bf16* dst = hs1T + (size_t)n*512*512;
    for (int c = threadIdx.x; c < 512; c += 256) {
        int frow = c >> 3, tch = c & 7;
        bf16 tmp[8];
        #pragma unroll
        for (int j = 0; j < 8; j++) tmp[j] = tile[tch*8+j][frow];
        *(uint4*)(dst + (size_t)(fX*64+frow)*512 + tX*64 + tch*8) = *(uint4*)tmp;
    }
}

__global__ __launch_bounds__(256, 2)
void ctx_gemm(const bf16* __restrict__ P, const bf16* __restrict__ hs1T,
              bf16* __restrict__ ctx)
{
    __shared__ char smem[64*144*2];
    int n = blockIdx.z, tm = blockIdx.x, tn = blockIdx.y;
    const bf16* A0 = P    + (size_t)n*512*512 + (size_t)tm*64*512;
    const bf16* B0 = hs1T + (size_t)n*512*512 + (size_t)tn*64*512;
    floatx16 acc = gemm_loop(A0, B0, 512, 512, 512, 64, smem);
    int wave = threadIdx.x >> 6, lane = threadIdx.x & 63;
    int mi = wave & 1, ni = wave >> 1;
    #pragma unroll
    for (int r = 0; r < 16; r++) {
        int row = tm*64 + mi*32 + (r&3) + 8*(r>>2) + 4*(lane>>5);
        int col = tn*64 + ni*32 + (lane&31);
        ctx[((size_t)n*512 + row)*512 + col] = (bf16)acc[r];
    }
}

__global__ __launch_bounds__(256, 2)
void fc1_gemm(const bf16* __restrict__ ctx, const bf16* __restrict__ hs1,
              const bf16* __restrict__ wb, const float* __restrict__ b,
              float* __restrict__ outp)
{
    __shared__ char smem[64*144*2];
    const int tid = threadIdx.x;
    const int wave = tid >> 6, lane = tid & 63;
    const int mi = wave & 1, ni = wave >> 1;
    const int l31 = lane & 31, lh = lane >> 5;
    char* At = smem;
    char* Bt = smem + 64*144;
    const int m0 = blockIdx.x*64;
    floatx16 acc;
    #pragma unroll
    for (int r = 0; r < 16; r++) acc[r] = 0.0f;

    for (int kc = 0; kc < 1024; kc += 64) {
        const bf16* Asrc = (kc < 512) ? ctx : hs1;
        const int koff = kc & 511;
        __syncthreads();
        for (int c = tid; c < 1024; c += 256) {
            int which = c >> 9, idx = c & 511;
            int row = idx >> 3, kch = idx & 7;
            uint4 v;
            if (which == 0) {
                v = *(const uint4*)(Asrc + (size_t)(m0+row)*512 + koff + kch*8);
                *(uint4*)(At + row*144 + kch*16) = v;
            } else {
                if (row < 50) v = *(const uint4*)(wb + (size_t)row*1024 + kc + kch*8);
                else          v = make_uint4(0,0,0,0);
                *(uint4*)(Bt + row*144 + kch*16) = v;
            }
        }
        __syncthreads();
        #pragma unroll
        for (int ks = 0; ks < 4; ks++) {
            bf16x8 a = *(const bf16x8*)(At + (mi*32 + l31)*144 + ks*32 + lh*16);
            bf16x8 bb = *(const bf16x8*)(Bt + (ni*32 + l31)*144 + ks*32 + lh*16);
            acc = __builtin_amdgcn_mfma_f32_32x32x16_bf16(a, bb, acc, 0, 0, 0);
        }
    }
    #pragma unroll
    for (int r = 0; r < 16; r++) {
        int row = m0 + mi*32 + (r&3) + 8*(r>>2) + 4*lh;
        int col = ni*32 + l31;
        if (col < 50) {
            float v = acc[r] + b[col];
            outp[(size_t)row*50 + col] = fmaxf(v, 0.0f);
        }
    }
}

__global__ __launch_bounds__(256, 4)
void bn_stats(const float* __restrict__ fc1out, float* __restrict__ stats)
{
    __shared__ float sh[512];
    int c = blockIdx.x;
    float s = 0.0f, ss = 0.0f;
    for (int i = threadIdx.x; i < 32768; i += 256) {
        int n = i >> 9, q = i & 511;
        float x = fc1out[(size_t)n*25600 + c*512 + q];
        s += x; ss += x*x;
    }
    sh[threadIdx.x] = s; sh[256 + threadIdx.x] = ss;
    __syncthreads();
    for (int o = 128; o > 0; o >>= 1) {
        if (threadIdx.x < o) {
            sh[threadIdx.x] += sh[threadIdx.x + o];
            sh[256+threadIdx.x] += sh[256+threadIdx.x + o];
        }
        __syncthreads();
    }
    if (threadIdx.x == 0) {
        float mean = sh[0] / 32768.0f;
        float var  = sh[256] / 32768.0f - mean*mean;
        stats[c]      = mean;
        stats[64 + c] = rsqrtf(var + 1e-5f);
    }
}

__global__ __launch_bounds__(256, 4)
void tail_kernel(const float* __restrict__ fc1out, const float* __restrict__ stats,
                 const float* __restrict__ bng, const float* __restrict__ bnb,
                 const float* __restrict__ fc2w, const float* __restrict__ fc2b,
                 const float* __restrict__ fc3w, const float* __restrict__ fc3b,
                 const float* __restrict__ fc4w, const float* __restrict__ fc4b,
                 float* __restrict__ outp)
{
    __shared__ float W2[1250], W3[250], B2[25], B3[10], W4[20], B4[2];
    __shared__ float G[50], Bb[50], MU[50], IS[50];
    for (int i = threadIdx.x; i < 1250; i += 256) W2[i] = fc2w[i];
    for (int i = threadIdx.x; i < 250;  i += 256) W3[i] = fc3w[i];
    if (threadIdx.x < 25) B2[threadIdx.x] = fc2b[threadIdx.x];
    if (threadIdx.x < 20) W4[threadIdx.x] = fc4w[threadIdx.x];
    if (threadIdx.x < 10) B3[threadIdx.x] = fc3b[threadIdx.x];
    if (threadIdx.x < 2)  B4[threadIdx.x] = fc4b[threadIdx.x];
    if (threadIdx.x < 50) {
        G[threadIdx.x]  = bng[threadIdx.x];
        Bb[threadIdx.x] = bnb[threadIdx.x];
        MU[threadIdx.x] = stats[threadIdx.x];
        IS[threadIdx.x] = stats[64 + threadIdx.x];
    }
    __syncthreads();
    int m = blockIdx.x*256 + threadIdx.x;
    int t = m & 511;
    const float* src = fc1out + (size_t)m*50;
    float x[50];
    #pragma unroll
    for (int c = 0; c < 50; c++) {
        int j = (t*50 + c) >> 9;
        x[c] = (src[c] - MU[j])*IS[j]*G[j] + Bb[j];
    }
    float y2[25];
    #pragma unroll
    for (int o = 0; o < 25; o++) {
        float a = B2[o];
        for (int c = 0; c < 50; c++) a += x[c]*W2[o*50+c];
        y2[o] = fmaxf(a, 0.0f);
    }
    float y3[10];
    #pragma unroll
    for (int o = 0; o < 10; o++) {
        float a = B3[o];
        for (int c = 0; c < 25; c++) a += y2[c]*W3[o*25+c];
        y3[o] = fmaxf(a, 0.0f);
    }
    #pragma unroll
    for (int o = 0; o < 2; o++) {
        float a = B4[o];
        for (int c = 0; c < 10; c++) a += y3[c]*W4[o*10+c];
        outp[(size_t)m*2 + o] = a;
    }
}

extern "C" void kernel_launch(void* const* d_in, const int* in_sizes, int n_in,
                              void* d_out, int out_size, void* d_ws, size_t ws_size,
                              hipStream_t stream)
{
    const float* x       = (const float*)d_in[0];
    const float* wih_l0f = (const float*)d_in[1];
    const float* whh_l0f = (const float*)d_in[2];
    const float* b_l0f   = (const float*)d_in[3];
    const float* wih_l0b = (const float*)d_in[4];
    const float* whh_l0b = (const float*)d_in[5];
    const float* b_l0b   = (const float*)d_in[6];
    const float* wih_l1f = (const float*)d_in[7];
    const float* whh_l1f = (const float*)d_in[8];
    const float* b_l1f   = (const float*)d_in[9];
    const float* wih_l1b = (const float*)d_in[10];
    const float* whh_l1b = (const float*)d_in[11];
    const float* b_l1b   = (const float*)d_in[12];
    const float* fc1w    = (const float*)d_in[13];
    const float* fc1b    = (const float*)d_in[14];
    const float* bng     = (const float*)d_in[15];
    const float* bnb     = (const float*)d_in[16];
    const float* fc2w    = (const float*)d_in[17];
    const float* fc2b    = (const float*)d_in[18];
    const float* fc3w    = (const float*)d_in[19];
    const float* fc3b    = (const float*)d_in[20];
    const float* fc4w    = (const float*)d_in[21];
    const float* fc4b    = (const float*)d_in[22];

    // ---- workspace layout ----
    char* ws = (char*)d_ws;
    float* stats  = (float*)ws;                        // 512 B
    bf16*  fc1wb  = (bf16*)(ws + 4096);                // 102400 B
    bf16*  hs0    = (bf16*)(ws + 131072);              // 32 MiB
    bf16*  hs1    = (bf16*)(ws + 33685504);            // 32 MiB
    float* xg     = (float*)(ws + 67239936);           // 128 MiB (one chunk)
    bf16*  wb0f   = (bf16*)(ws + 201457664);           // 256 KiB
    bf16*  wb0b   = (bf16*)(ws + 201719808);           // 256 KiB
    bf16*  wb1f   = (bf16*)(ws + 201981952);           // 1 MiB
    bf16*  wb1b   = (bf16*)(ws + 203030528);           // 1 MiB
    bf16*  Wp0f   = (bf16*)(ws + 204079104);           // 512 KiB
    bf16*  Wp0b   = (bf16*)(ws + 204603392);           // 512 KiB
    bf16*  Wp1f   = (bf16*)(ws + 205127680);           // 512 KiB
    bf16*  Wp1b   = (bf16*)(ws + 205651968);           // 512 KiB
    float* cst    = (float*)(ws + 206176256);          // 256 KiB
    // post-rec overlays (xg / weight packs dead by then):
    bf16*  ctx    = (bf16*)(ws + 67239936);            // 32 MiB
    float* S      = (float*)(ws + 100794368);          // 64 MiB
    bf16*  P      = (bf16*)(ws + 167903232);           // 32 MiB
    float* fc1out = (float*)(ws + 201457664);          // 6.25 MiB
    bf16*  hs1T   = (bf16*)S;

    // ---- weight prep ----
    f2b_kernel<<<200, 256, 0, stream>>>(fc1w, fc1wb, 51200);
    f2b_kernel<<<512, 256, 0, stream>>>(wih_l0f, wb0f, 131072);
    f2b_kernel<<<512, 256, 0, stream>>>(wih_l0b, wb0b, 131072);
    f2b_kernel<<<2048, 256, 0, stream>>>(wih_l1f, wb1f, 524288);
    f2b_kernel<<<2048, 256, 0, stream>>>(wih_l1b, wb1b, 524288);
    pack_whh<<<128, 256, 0, stream>>>(whh_l0f, Wp0f);
    pack_whh<<<128, 256, 0, stream>>>(whh_l0b, Wp0b);
    pack_whh<<<128, 256, 0, stream>>>(whh_l1f, Wp1f);
    pack_whh<<<128, 256, 0, stream>>>(whh_l1b, Wp1b);

    constexpr int REC_LDS = 131072 + 16384 + 2*2176;   // 151,808 B
    hipFuncSetAttribute(reinterpret_cast<const void*>(&rec_kernel),
                        hipFuncAttributeMaxDynamicSharedMemorySize, REC_LDS);

    dim3 gxg(256, 16, 2);
    // ---- layer 0 ----
    xg_gemm<128, true><<<gxg, 256, 0, stream>>>(x, wb0f, wb0b, b_l0f, b_l0b, xg, 0);
    rec_kernel<<<32, 512, REC_LDS, stream>>>(xg, Wp0f, Wp0b, hs0, cst, 0);
    xg_gemm<128, true><<<gxg, 256, 0, stream>>>(x, wb0f, wb0b, b_l0f, b_l0b, xg, 1);
    rec_kernel<<<32, 512, REC_LDS, stream>>>(xg, Wp0f, Wp0b, hs0, cst, 1);
    // ---- layer 1 ----
    xg_gemm<512, false><<<gxg, 256, 0, stream>>>(hs0, wb1f, wb1b, b_l1f, b_l1b, xg, 0);
    rec_kernel<<<32, 512, REC_LDS, stream>>>(xg, Wp1f, Wp1b, hs1, cst, 0);
    xg_gemm<512, false><<<gxg, 256, 0, stream>>>(hs0, wb1f, wb1b, b_l1f, b_l1b, xg, 1);
    rec_kernel<<<32, 512, REC_LDS, stream>>>(xg, Wp1f, Wp1b, hs1, cst, 1);

    // ---- attention + head ----
    dim3 g88(8, 8, 64);
    sgemm_scores<<<g88, 256, 0, stream>>>(hs1, S);
    softmax_rows<<<8192, 256, 0, stream>>>(S, P);
    transpose_nt<<<g88, 256, 0, stream>>>(hs1, hs1T);
    ctx_gemm<<<g88, 256, 0, stream>>>(P, hs1T, ctx);
    fc1_gemm<<<512, 256, 0, stream>>>(ctx, hs1, fc1wb, fc1b, fc1out);
    bn_stats<<<50, 256, 0, stream>>>(fc1out, stats);
    tail_kernel<<<128, 256, 0, stream>>>(fc1out, stats, bng, bnb, fc2w, fc2b,
                                         fc3w, fc3b, fc4w, fc4b, (float*)d_out);
    (void)in_sizes; (void)n_in; (void)out_size; (void)ws_size;
}

// Round 8
// 2380.770 us; speedup vs baseline: 2.1503x; 1.2987x over previous
//
#include <hip/hip_runtime.h>
#include <hip/hip_bf16.h>

typedef __bf16 bf16;
typedef __bf16 bf16x8 __attribute__((ext_vector_type(8)));
typedef float floatx4 __attribute__((ext_vector_type(4)));
typedef float floatx16 __attribute__((ext_vector_type(16)));

#define TSEQ 512
#define MFMA16 __builtin_amdgcn_mfma_f32_16x16x32_bf16

__device__ __forceinline__ float sigm(float x){ return 1.0f/(1.0f + __expf(-x)); }
__device__ __forceinline__ float tanh_fast(float x){
    float e = __expf(2.0f*x);
    return 1.0f - 2.0f/(e + 1.0f);   // correct limits at +-inf
}

// fp32 -> bf16 converter
__global__ __launch_bounds__(256, 4)
void f2b_kernel(const float* __restrict__ in, bf16* __restrict__ out, int n)
{
    int i = blockIdx.x*256 + threadIdx.x;
    if (i < n) out[i] = (bf16)in[i];
}

// ---------------------------------------------------------------------------
// Pack Whh (1024 x 256 fp32) into MFMA-16x16x32 B-frag-major bf16 layout:
// Wp[ntile 0..63][kstep 0..7][lane 0..63][e 0..7], value =
//   Whh[gatecol = ntile*16 + (lane&15)][k = kstep*32 + (lane>>4)*8 + e]
// ---------------------------------------------------------------------------
__global__ __launch_bounds__(256, 4)
void pack_whh(const float* __restrict__ whh, bf16* __restrict__ wp)
{
    int idx = blockIdx.x*256 + threadIdx.x;
    if (idx >= 32768) return;
    int lane = idx & 63, ks = (idx >> 6) & 7, nt = idx >> 9;
    int row = nt*16 + (lane & 15);
    int k0  = ks*32 + (lane >> 4)*8;
    const float* src = whh + (size_t)row*256 + k0;
    bf16x8 v;
    #pragma unroll
    for (int e = 0; e < 8; e++) v[e] = (bf16)src[e];
    ((bf16x8*)wp)[idx] = v;
}

// ---------------------------------------------------------------------------
// xg = x @ Wih^T + bias for one 256-step chunk, both dirs (blockIdx.z).
// Plane layout (16 KiB per (rec-block, sloc)):
//   xg[(d*16+bg)*256 + sloc][w 0..7][j 0..7][l15 0..15][r 0..3] fp32
// A-tile = 64 rows = (16 slocs x 4 seqs, r-fast): row = slot*4 + r.
// Epilogue: each thread writes 4 coalesced float4 (consecutive r).
// Grid (256,16,2): bx = bg*16 + sg, by = coltile, bz = dir.
// ---------------------------------------------------------------------------
template<int DIN, bool XF32>
__global__ __launch_bounds__(256, 2)
void xg_gemm(const void* __restrict__ xin,
             const bf16* __restrict__ wbf, const bf16* __restrict__ wbb,
             const float* __restrict__ bf_, const float* __restrict__ bb_,
             float* __restrict__ xg, int chunk)
{
    __shared__ char smem[64*144*2];
    const int tid = threadIdx.x;
    const int wv = tid >> 6, ln = tid & 63;
    const int mi = wv & 1, ni = wv >> 1;
    const int l31 = ln & 31, lh = ln >> 5;
    char* At = smem;
    char* Bt = smem + 64*144;

    const int d   = blockIdx.z;
    const int bg  = blockIdx.x >> 4;        // seq group (4 seqs)
    const int sg  = blockIdx.x & 15;        // sloc group (16 slocs)
    const int n0  = blockIdx.y * 64;
    const bf16*  wb   = d ? wbb : wbf;
    const float* bias = d ? bb_ : bf_;
    const int seq0  = bg*4;
    const int tbase = d ? (511 - (chunk*256 + sg*16)) : (chunk*256 + sg*16);
    const int stp   = d ? -1 : 1;

    floatx16 acc;
    #pragma unroll
    for (int r = 0; r < 16; r++) acc[r] = 0.0f;

    for (int kc = 0; kc < DIN; kc += 64) {
        __syncthreads();
        for (int c = tid; c < 1024; c += 256) {
            const int which = c >> 9, idx = c & 511;
            const int row = idx >> 3, k8 = idx & 7;
            if (which == 0) {
                const int trow = tbase + (row >> 2)*stp;
                const int seq  = seq0 + (row & 3);
                if constexpr (XF32) {
                    const float* src = (const float*)xin
                        + ((size_t)seq*TSEQ + trow)*DIN + kc + k8*8;
                    const float4 lo = *(const float4*)src;
                    const float4 hi = *(const float4*)(src+4);
                    bf16 tmp[8] = {(bf16)lo.x,(bf16)lo.y,(bf16)lo.z,(bf16)lo.w,
                                   (bf16)hi.x,(bf16)hi.y,(bf16)hi.z,(bf16)hi.w};
                    *(uint4*)(At + row*144 + k8*16) = *(uint4*)tmp;
                } else {
                    const bf16* src = (const bf16*)xin
                        + ((size_t)seq*TSEQ + trow)*DIN + kc + k8*8;
                    *(uint4*)(At + row*144 + k8*16) = *(const uint4*)src;
                }
            } else {
                *(uint4*)(Bt + row*144 + k8*16) =
                    *(const uint4*)(wb + (size_t)(n0+row)*DIN + kc + k8*8);
            }
        }
        __syncthreads();
        #pragma unroll
        for (int ks = 0; ks < 4; ks++) {
            bf16x8 a = *(const bf16x8*)(At + (mi*32 + l31)*144 + ks*32 + lh*16);
            bf16x8 b = *(const bf16x8*)(Bt + (ni*32 + l31)*144 + ks*32 + lh*16);
            acc = __builtin_amdgcn_mfma_f32_32x32x16_bf16(a, b, acc, 0, 0, 0);
        }
    }
    const int col = n0 + ni*32 + l31;
    const int nt = col >> 4, l15c = col & 15;
    const int wq = nt & 7, jq = nt >> 3;
    const float bv = bias[col];
    char* pb = (char*)xg + ((size_t)((d*16 + bg)*256 + sg*16))*16384
             + (size_t)(((wq*8 + jq)*16 + l15c)*16);
    #pragma unroll
    for (int g = 0; g < 4; g++) {
        const int slotL = mi*8 + 2*g + lh;   // sloc offset within group
        float4 v = make_float4(acc[4*g+0]+bv, acc[4*g+1]+bv,
                               acc[4*g+2]+bv, acc[4*g+3]+bv);
        *(float4*)(pb + (size_t)slotL*16384) = v;
    }
}

// ---------------------------------------------------------------------------
// Batch-split recurrence v8. 32 blocks = 2 dir x 16 groups of 4 seqs; 512 thr
// (8 waves, 2/SIMD). Zero inter-block traffic.
// Weight tiers per wave (ntile = j*8+w): j=0..4 reg (AGPR), j=5,6 LDS
// (16 ntiles, 128 KiB), j=7 streamed from L2 (SB, refilled each step).
// v8 changes vs v7 (VALUBusy ~59%/CU was the bottleneck):
//  (1) exact cell ownership: lq>>1 picks col-half (jj), lq&1 picks seq-pair
//      (lo) -> 2 cells/thread, transcendental chain HALVED (was 2x dup).
//  (2) pre-barrier C-in preload: ring slices are wave-private, so after the
//      write-late ds_writes we lgkmcnt(0) and preload next step's acc BEFORE
//      the barrier -> post-barrier path is A-read -> MFMA immediately.
//  (3) incremental hsout pointer (no per-step 64-bit addr recompute).
// Light barrier (lgkmcnt only) kept from v7; global ops float across steps.
// ---------------------------------------------------------------------------
__global__ __launch_bounds__(512, 1)
void rec_kernel(const float* __restrict__ xg,
                const bf16* __restrict__ WpF, const bf16* __restrict__ WpB,
                bf16* __restrict__ hsout, float* __restrict__ cst, int chunk)
{
    extern __shared__ char smem[];
    bf16x8* Wlds = (bf16x8*)smem;            // ntiles 40..55: 128 KiB
    char* ring = smem + 131072;              // xg plane slot: 16 KiB
    char* hb0  = smem + 147456;              // 4 rows x 544 B
    char* hb1  = hb0 + 2176;

    const int tid = threadIdx.x;
    const int w = tid >> 6, l = tid & 63;
    const int l15 = l & 15, lq = l >> 4;
    const int jj = lq >> 1, lo = lq & 1;
    const int blk = blockIdx.x;
    const int d = blk >> 4, bg = blk & 15;
    const bf16x8* Wp = (const bf16x8*)(d ? WpB : WpF);

    // LDS weight tier: ntiles 40..55 (j=5,6 for all waves)
    for (int i = tid; i < 8192; i += 512) Wlds[i] = Wp[40*512 + i];

    // reg tier j=0..4 (nt = j*8+w)
    bf16x8 WR[5][8];
    #pragma unroll
    for (int j = 0; j < 5; j++)
        #pragma unroll
        for (int ks = 0; ks < 8; ks++)
            WR[j][ks] = Wp[((j*8 + w)*8 + ks)*64 + l];
    // streamed tier j=7 (nt = 56+w)
    const int sbBase = ((56 + w)*8)*64 + l;
    bf16x8 SB[8];
    #pragma unroll
    for (int ks = 0; ks < 8; ks++) SB[ks] = Wp[sbBase + ks*64];

    // h buffer init (sl=0 reads hb0)
    if (chunk == 0) {
        if (tid < 272) ((uint4*)hb0)[tid] = make_uint4(0,0,0,0); // hb0+hb1
    } else if (tid < 128) {
        const int tprev = d ? (512 - chunk*256) : (chunk*256 - 1);
        const int row = tid >> 5, c8 = (tid & 31)*8;
        uint4 v = *(const uint4*)(hsout
            + ((size_t)(bg*4 + row)*TSEQ + tprev)*512 + d*256 + c8);
        *(uint4*)(hb0 + row*544 + c8*2) = v;
    }

    // c-state: 2 cells (seqs lo*2, lo*2+1; col hcol)
    float cs[2];
    if (chunk == 0) { cs[0]=cs[1]=0.0f; }
    else {
        float2 cv = ((const float2*)cst)[blk*512 + tid];
        cs[0]=cv.x; cs[1]=cv.y;
    }

    const char* xgp = (const char*)xg + ((size_t)blk*256)*16384;
    const int rslice = w*2048;

    // prologue: fill ring with plane sl=0 (each wave its own 2 KiB slice)
    {
        const char* pn = xgp + (size_t)rslice;
        uint4 s0 = *(const uint4*)(pn + l*16);
        uint4 s1 = *(const uint4*)(pn + 1024 + l*16);
        *(uint4*)(ring + rslice + l*16) = s0;
        *(uint4*)(ring + rslice + 1024 + l*16) = s1;
    }
    __syncthreads();

    // preload acc for sl=0 (own wave slice; synced above)
    floatx4 acc[8];
    #pragma unroll
    for (int j = 0; j < 8; j++)
        acc[j] = *(const floatx4*)(ring + rslice + (j*16 + l15)*16);

    const int aoff = (l15 & 3)*544 + lq*16;
    const int i5b = w*512 + l;               // Wlds idx j=5 (+ks*64)
    const int i6b = (8 + w)*512 + l;         // j=6
    const int hcol = jj*128 + w*16 + l15;
    bf16* hgp = hsout + (size_t)(bg*4 + lo*2)*TSEQ*512 + d*256 + hcol
              + (size_t)(d ? (511 - chunk*256) : (chunk*256))*512;
    const long hstep = d ? -512 : 512;

    for (int sl = 0; sl < 256; ++sl) {
        const char* hr = (sl & 1) ? hb1 : hb0;
        char* hw = (sl & 1) ? hb0 : hb1;

        // ---- issue-early: next plane global loads (consumed at bottom) ----
        uint4 stg0, stg1;
        if (sl < 255) {
            const char* pn = xgp + (size_t)(sl + 1)*16384 + rslice;
            stg0 = *(const uint4*)(pn + l*16);
            stg1 = *(const uint4*)(pn + 1024 + l*16);
        }

        // ---- MFMA: gates = xg + h_prev @ Whh^T (acc preloaded) ----
        #pragma unroll
        for (int ks = 0; ks < 8; ks++) {
            bf16x8 A = *(const bf16x8*)(hr + aoff + ks*64);
            acc[0] = MFMA16(A, WR[0][ks], acc[0], 0,0,0);
            acc[1] = MFMA16(A, WR[1][ks], acc[1], 0,0,0);
            acc[2] = MFMA16(A, WR[2][ks], acc[2], 0,0,0);
            acc[3] = MFMA16(A, WR[3][ks], acc[3], 0,0,0);
            acc[4] = MFMA16(A, WR[4][ks], acc[4], 0,0,0);
            acc[5] = MFMA16(A, Wlds[i5b + ks*64], acc[5], 0,0,0);
            acc[6] = MFMA16(A, Wlds[i6b + ks*64], acc[6], 0,0,0);
            acc[7] = MFMA16(A, SB[ks], acc[7], 0,0,0);
        }
        // refill streamed tier for next step (floats across the light barrier)
        if (sl < 255) {
            int zx;
            asm volatile("s_mov_b32 %0, 0" : "=s"(zx));  // defeat LICM
            #pragma unroll
            for (int ks = 0; ks < 8; ks++) SB[ks] = Wp[sbBase + ks*64 + zx];
        }

        // ---- extraction (static reg indices + 3 cndmask) + cell math ----
        // gate g value for cell rr: acc[2g + jj][lo*2 + rr]
        float hv[2];
        #pragma unroll
        for (int rr = 0; rr < 2; rr++) {
            const float gIl = jj ? acc[1][rr]   : acc[0][rr];
            const float gIh = jj ? acc[1][2+rr] : acc[0][2+rr];
            const float gI  = lo ? gIh : gIl;
            const float gFl = jj ? acc[3][rr]   : acc[2][rr];
            const float gFh = jj ? acc[3][2+rr] : acc[2][2+rr];
            const float gF  = lo ? gFh : gFl;
            const float gGl = jj ? acc[5][rr]   : acc[4][rr];
            const float gGh = jj ? acc[5][2+rr] : acc[4][2+rr];
            const float gG  = lo ? gGh : gGl;
            const float gOl = jj ? acc[7][rr]   : acc[6][rr];
            const float gOh = jj ? acc[7][2+rr] : acc[6][2+rr];
            const float gO  = lo ? gOh : gOl;
            const float cn = sigm(gF)*cs[rr] + sigm(gI)*tanh_fast(gG);
            cs[rr] = cn;
            hv[rr] = sigm(gO)*tanh_fast(cn);
        }

        // ---- write-late ring update (wave-private) ----
        if (sl < 255) {
            *(uint4*)(ring + rslice + l*16) = stg0;
            *(uint4*)(ring + rslice + 1024 + l*16) = stg1;
        }

        // ---- h stores: 2 cells -> LDS (next A) + global hsout ----
        #pragma unroll
        for (int rr = 0; rr < 2; rr++) {
            const bf16 hb_ = (bf16)hv[rr];
            *(bf16*)(hw + (lo*2 + rr)*544 + hcol*2) = hb_;
            hgp[(size_t)rr*TSEQ*512] = hb_;
        }
        hgp += hstep;

        // ---- pre-barrier C-in preload for sl+1 (own slice just written) ----
        if (sl < 255) {
            __builtin_amdgcn_sched_barrier(0);
            asm volatile("s_waitcnt lgkmcnt(0)" ::: "memory");
            __builtin_amdgcn_sched_barrier(0);
            #pragma unroll
            for (int j = 0; j < 8; j++)
                acc[j] = *(const floatx4*)(ring + rslice + (j*16 + l15)*16);
        }

        // ---- light barrier: order ONLY the LDS h-buffer hand-off ----
        __builtin_amdgcn_sched_barrier(0);
        asm volatile("s_waitcnt lgkmcnt(0)\n\ts_barrier" ::: "memory");
        __builtin_amdgcn_sched_barrier(0);
    }

    ((float2*)cst)[blk*512 + tid] = make_float2(cs[0], cs[1]);
}

// ---------------------------------------------------------------------------
// Shared 64x64 bf16 GEMM main loop (attention chain) — unchanged.
// ---------------------------------------------------------------------------
__device__ __forceinline__ floatx16 gemm_loop(const bf16* __restrict__ A0,
                                              const bf16* __restrict__ Bt0,
                                              int lda, int ldb, int K, int brows,
                                              char* smem)
{
    const int tid = threadIdx.x;
    const int wave = tid >> 6, lane = tid & 63;
    const int mi = wave & 1, ni = wave >> 1;
    const int l31 = lane & 31, lh = lane >> 5;
    char* At = smem;
    char* Bt = smem + 64*144;
    floatx16 acc;
    #pragma unroll
    for (int r = 0; r < 16; r++) acc[r] = 0.0f;

    for (int kc = 0; kc < K; kc += 64) {
        __syncthreads();
        for (int c = tid; c < 1024; c += 256) {
            int which = c >> 9;
            int idx = c & 511;
            int row = idx >> 3, kch = idx & 7;
            uint4 v;
            if (which == 0) {
                v = *(const uint4*)(A0 + (size_t)row*lda + kc + kch*8);
                *(uint4*)(At + row*144 + kch*16) = v;
            } else {
                if (row < brows) v = *(const uint4*)(Bt0 + (size_t)row*ldb + kc + kch*8);
                else             v = make_uint4(0,0,0,0);
                *(uint4*)(Bt + row*144 + kch*16) = v;
            }
        }
        __syncthreads();
        #pragma unroll
        for (int ks = 0; ks < 4; ks++) {
            bf16x8 a = *(const bf16x8*)(At + (mi*32 + l31)*144 + ks*32 + lh*16);
            bf16x8 b = *(const bf16x8*)(Bt + (ni*32 + l31)*144 + ks*32 + lh*16);
            acc = __builtin_amdgcn_mfma_f32_32x32x16_bf16(a, b, acc, 0, 0, 0);
        }
    }
    return acc;
}

__global__ __launch_bounds__(256, 2)
void sgemm_scores(const bf16* __restrict__ hs1, float* __restrict__ S)
{
    __shared__ char smem[64*144*2];
    int n = blockIdx.z, tm = blockIdx.x, tn = blockIdx.y;
    const bf16* base = hs1 + (size_t)n*512*512;
    floatx16 acc = gemm_loop(base + (size_t)tm*64*512, base + (size_t)tn*64*512,
                             512, 512, 512, 64, smem);
    int wave = threadIdx.x >> 6, lane = threadIdx.x & 63;
    int mi = wave & 1, ni = wave >> 1;
    #pragma unroll
    for (int r = 0; r < 16; r++) {
        int row = tm*64 + mi*32 + (r&3) + 8*(r>>2) + 4*(lane>>5);
        int col = tn*64 + ni*32 + (lane&31);
        S[(size_t)n*512*512 + (size_t)row*512 + col] = acc[r];
    }
}

__global__ __launch_bounds__(256, 4)
void softmax_rows(const float* __restrict__ S, bf16* __restrict__ P)
{
    int row = blockIdx.x*4 + (threadIdx.x >> 6);
    int lane = threadIdx.x & 63;
    const float* src = S + (size_t)row*512 + lane*8;
    float4 a = *(const float4*)(src);
    float4 b = *(const float4*)(src + 4);
    float v[8] = {a.x,a.y,a.z,a.w,b.x,b.y,b.z,b.w};
    float m = v[0];
    #pragma unroll
    for (int j = 1; j < 8; j++) m = fmaxf(m, v[j]);
    #pragma unroll
    for (int off = 32; off > 0; off >>= 1) m = fmaxf(m, __shfl_xor(m, off));
    float s = 0.0f;
    #pragma unroll
    for (int j = 0; j < 8; j++) { v[j] = __expf(v[j]-m); s += v[j]; }
    #pragma unroll
    for (int off = 32; off > 0; off >>= 1) s += __shfl_xor(s, off);
    float inv = 1.0f/s;
    union { uint4 u; bf16 h[8]; } pk;
    #pragma unroll
    for (int j = 0; j < 8; j++) pk.h[j] = (bf16)(v[j]*inv);
    *(uint4*)(P + (size_t)row*512 + lane*8) = pk.u;
}

__global__ __launch_bounds__(256, 2)
void transpose_nt(const bf16* __restrict__ hs1, bf16* __restrict__ hs1T)
{
    __shared__ bf16 tile[64][72];
    int n = blockIdx.z, tX = blockIdx.x, fX = blockIdx.y;
    const bf16* src = hs1 + (size_t)n*512*512;
    for (int c = threadIdx.x; c < 512; c += 256) {
        int row = c >> 3, kch = c & 7;
        *(uint4*)(&tile[row][kch*8]) =
            *(const uint4*)(src + (size_t)(tX*64+row)*512 + fX*64 + kch*8);
    }
    __syncthreads();
    bf16* dst = hs1T + (size_t)n*512*512;
    for (int c = threadIdx.x; c < 512; c += 256) {
        int frow = c >> 3, tch = c & 7;
        bf16 tmp[8];
        #pragma unroll
        for (int j = 0; j < 8; j++) tmp[j] = tile[tch*8+j][frow];
        *(uint4*)(dst + (size_t)(fX*64+frow)*512 + tX*64 + tch*8) = *(uint4*)tmp;
    }
}

__global__ __launch_bounds__(256, 2)
void ctx_gemm(const bf16* __restrict__ P, const bf16* __restrict__ hs1T,
              bf16* __restrict__ ctx)
{
    __shared__ char smem[64*144*2];
    int n = blockIdx.z, tm = blockIdx.x, tn = blockIdx.y;
    const bf16* A0 = P    + (size_t)n*512*512 + (size_t)tm*64*512;
    const bf16* B0 = hs1T + (size_t)n*512*512 + (size_t)tn*64*512;
    floatx16 acc = gemm_loop(A0, B0, 512, 512, 512, 64, smem);
    int wave = threadIdx.x >> 6, lane = threadIdx.x & 63;
    int mi = wave & 1, ni = wave >> 1;
    #pragma unroll
    for (int r = 0; r < 16; r++) {
        int row = tm*64 + mi*32 + (r&3) + 8*(r>>2) + 4*(lane>>5);
        int col = tn*64 + ni*32 + (lane&31);
        ctx[((size_t)n*512 + row)*512 + col] = (bf16)acc[r];
    }
}

__global__ __launch_bounds__(256, 2)
void fc1_gemm(const bf16* __restrict__ ctx, const bf16* __restrict__ hs1,
              const bf16* __restrict__ wb, const float* __restrict__ b,
              float* __restrict__ outp)
{
    __shared__ char smem[64*144*2];
    const int tid = threadIdx.x;
    const int wave = tid >> 6, lane = tid & 63;
    const int mi = wave & 1, ni = wave >> 1;
    const int l31 = lane & 31, lh = lane >> 5;
    char* At = smem;
    char* Bt = smem + 64*144;
    const int m0 = blockIdx.x*64;
    floatx16 acc;
    #pragma unroll
    for (int r = 0; r < 16; r++) acc[r] = 0.0f;

    for (int kc = 0; kc < 1024; kc += 64) {
        const bf16* Asrc = (kc < 512) ? ctx : hs1;
        const int koff = kc & 511;
        __syncthreads();
        for (int c = tid; c < 1024; c += 256) {
            int which = c >> 9, idx = c & 511;
            int row = idx >> 3, kch = idx & 7;
            uint4 v;
            if (which == 0) {
                v = *(const uint4*)(Asrc + (size_t)(m0+row)*512 + koff + kch*8);
                *(uint4*)(At + row*144 + kch*16) = v;
            } else {
                if (row < 50) v = *(const uint4*)(wb + (size_t)row*1024 + kc + kch*8);
                else          v = make_uint4(0,0,0,0);
                *(uint4*)(Bt + row*144 + kch*16) = v;
            }
        }
        __syncthreads();
        #pragma unroll
        for (int ks = 0; ks < 4; ks++) {
            bf16x8 a = *(const bf16x8*)(At + (mi*32 + l31)*144 + ks*32 + lh*16);
            bf16x8 bb = *(const bf16x8*)(Bt + (ni*32 + l31)*144 + ks*32 + lh*16);
            acc = __builtin_amdgcn_mfma_f32_32x32x16_bf16(a, bb, acc, 0, 0, 0);
        }
    }
    #pragma unroll
    for (int r = 0; r < 16; r++) {
        int row = m0 + mi*32 + (r&3) + 8*(r>>2) + 4*lh;
        int col = ni*32 + l31;
        if (col < 50) {
            float v = acc[r] + b[col];
            outp[(size_t)row*50 + col] = fmaxf(v, 0.0f);
        }
    }
}

__global__ __launch_bounds__(256, 4)
void bn_stats(const float* __restrict__ fc1out, float* __restrict__ stats)
{
    __shared__ float sh[512];
    int c = blockIdx.x;
    float s = 0.0f, ss = 0.0f;
    for (int i = threadIdx.x; i < 32768; i += 256) {
        int n = i >> 9, q = i & 511;
        float x = fc1out[(size_t)n*25600 + c*512 + q];
        s += x; ss += x*x;
    }
    sh[threadIdx.x] = s; sh[256 + threadIdx.x] = ss;
    __syncthreads();
    for (int o = 128; o > 0; o >>= 1) {
        if (threadIdx.x < o) {
            sh[threadIdx.x] += sh[threadIdx.x + o];
            sh[256+threadIdx.x] += sh[256+threadIdx.x + o];
        }
        __syncthreads();
    }
    if (threadIdx.x == 0) {
        float mean = sh[0] / 32768.0f;
        float var  = sh[256] / 32768.0f - mean*mean;
        stats[c]      = mean;
        stats[64 + c] = rsqrtf(var + 1e-5f);
    }
}

__global__ __launch_bounds__(256, 4)
void tail_kernel(const float* __restrict__ fc1out, const float* __restrict__ stats,
                 const float* __restrict__ bng, const float* __restrict__ bnb,
                 const float* __restrict__ fc2w, const float* __restrict__ fc2b,
                 const float* __restrict__ fc3w, const float* __restrict__ fc3b,
                 const float* __restrict__ fc4w, const float* __restrict__ fc4b,
                 float* __restrict__ outp)
{
    __shared__ float W2[1250], W3[250], B2[25], B3[10], W4[20], B4[2];
    __shared__ float G[50], Bb[50], MU[50], IS[50];
    for (int i = threadIdx.x; i < 1250; i += 256) W2[i] = fc2w[i];
    for (int i = threadIdx.x; i < 250;  i += 256) W3[i] = fc3w[i];
    if (threadIdx.x < 25) B2[threadIdx.x] = fc2b[threadIdx.x];
    if (threadIdx.x < 20) W4[threadIdx.x] = fc4w[threadIdx.x];
    if (threadIdx.x < 10) B3[threadIdx.x] = fc3b[threadIdx.x];
    if (threadIdx.x < 2)  B4[threadIdx.x] = fc4b[threadIdx.x];
    if (threadIdx.x < 50) {
        G[threadIdx.x]  = bng[threadIdx.x];
        Bb[threadIdx.x] = bnb[threadIdx.x];
        MU[threadIdx.x] = stats[threadIdx.x];
        IS[threadIdx.x] = stats[64 + threadIdx.x];
    }
    __syncthreads();
    int m = blockIdx.x*256 + threadIdx.x;
    int t = m & 511;
    const float* src = fc1out + (size_t)m*50;
    float x[50];
    #pragma unroll
    for (int c = 0; c < 50; c++) {
        int j = (t*50 + c) >> 9;
        x[c] = (src[c] - MU[j])*IS[j]*G[j] + Bb[j];
    }
    float y2[25];
    #pragma unroll
    for (int o = 0; o < 25; o++) {
        float a = B2[o];
        for (int c = 0; c < 50; c++) a += x[c]*W2[o*50+c];
        y2[o] = fmaxf(a, 0.0f);
    }
    float y3[10];
    #pragma unroll
    for (int o = 0; o < 10; o++) {
        float a = B3[o];
        for (int c = 0; c < 25; c++) a += y2[c]*W3[o*25+c];
        y3[o] = fmaxf(a, 0.0f);
    }
    #pragma unroll
    for (int o = 0; o < 2; o++) {
        float a = B4[o];
        for (int c = 0; c < 10; c++) a += y3[c]*W4[o*10+c];
        outp[(size_t)m*2 + o] = a;
    }
}

extern "C" void kernel_launch(void* const* d_in, const int* in_sizes, int n_in,
                              void* d_out, int out_size, void* d_ws, size_t ws_size,
                              hipStream_t stream)
{
    const float* x       = (const float*)d_in[0];
    const float* wih_l0f = (const float*)d_in[1];
    const float* whh_l0f = (const float*)d_in[2];
    const float* b_l0f   = (const float*)d_in[3];
    const float* wih_l0b = (const float*)d_in[4];
    const float* whh_l0b = (const float*)d_in[5];
    const float* b_l0b   = (const float*)d_in[6];
    const float* wih_l1f = (const float*)d_in[7];
    const float* whh_l1f = (const float*)d_in[8];
    const float* b_l1f   = (const float*)d_in[9];
    const float* wih_l1b = (const float*)d_in[10];
    const float* whh_l1b = (const float*)d_in[11];
    const float* b_l1b   = (const float*)d_in[12];
    const float* fc1w    = (const float*)d_in[13];
    const float* fc1b    = (const float*)d_in[14];
    const float* bng     = (const float*)d_in[15];
    const float* bnb     = (const float*)d_in[16];
    const float* fc2w    = (const float*)d_in[17];
    const float* fc2b    = (const float*)d_in[18];
    const float* fc3w    = (const float*)d_in[19];
    const float* fc3b    = (const float*)d_in[20];
    const float* fc4w    = (const float*)d_in[21];
    const float* fc4b    = (const float*)d_in[22];

    // ---- workspace layout ----
    char* ws = (char*)d_ws;
    float* stats  = (float*)ws;                        // 512 B
    bf16*  fc1wb  = (bf16*)(ws + 4096);                // 102400 B
    bf16*  hs0    = (bf16*)(ws + 131072);              // 32 MiB
    bf16*  hs1    = (bf16*)(ws + 33685504);            // 32 MiB
    float* xg     = (float*)(ws + 67239936);           // 128 MiB (one chunk)
    bf16*  wb0f   = (bf16*)(ws + 201457664);           // 256 KiB
    bf16*  wb0b   = (bf16*)(ws + 201719808);           // 256 KiB
    bf16*  wb1f   = (bf16*)(ws + 201981952);           // 1 MiB
    bf16*  wb1b   = (bf16*)(ws + 203030528);           // 1 MiB
    bf16*  Wp0f   = (bf16*)(ws + 204079104);           // 512 KiB
    bf16*  Wp0b   = (bf16*)(ws + 204603392);           // 512 KiB
    bf16*  Wp1f   = (bf16*)(ws + 205127680);           // 512 KiB
    bf16*  Wp1b   = (bf16*)(ws + 205651968);           // 512 KiB
    float* cst    = (float*)(ws + 206176256);          // 256 KiB
    // post-rec overlays (xg / weight packs dead by then):
    bf16*  ctx    = (bf16*)(ws + 67239936);            // 32 MiB
    float* S      = (float*)(ws + 100794368);          // 64 MiB
    bf16*  P      = (bf16*)(ws + 167903232);           // 32 MiB
    float* fc1out = (float*)(ws + 201457664);          // 6.25 MiB
    bf16*  hs1T   = (bf16*)S;

    // ---- weight prep ----
    f2b_kernel<<<200, 256, 0, stream>>>(fc1w, fc1wb, 51200);
    f2b_kernel<<<512, 256, 0, stream>>>(wih_l0f, wb0f, 131072);
    f2b_kernel<<<512, 256, 0, stream>>>(wih_l0b, wb0b, 131072);
    f2b_kernel<<<2048, 256, 0, stream>>>(wih_l1f, wb1f, 524288);
    f2b_kernel<<<2048, 256, 0, stream>>>(wih_l1b, wb1b, 524288);
    pack_whh<<<128, 256, 0, stream>>>(whh_l0f, Wp0f);
    pack_whh<<<128, 256, 0, stream>>>(whh_l0b, Wp0b);
    pack_whh<<<128, 256, 0, stream>>>(whh_l1f, Wp1f);
    pack_whh<<<128, 256, 0, stream>>>(whh_l1b, Wp1b);

    constexpr int REC_LDS = 131072 + 16384 + 2*2176;   // 151,808 B
    hipFuncSetAttribute(reinterpret_cast<const void*>(&rec_kernel),
                        hipFuncAttributeMaxDynamicSharedMemorySize, REC_LDS);

    dim3 gxg(256, 16, 2);
    // ---- layer 0 ----
    xg_gemm<128, true><<<gxg, 256, 0, stream>>>(x, wb0f, wb0b, b_l0f, b_l0b, xg, 0);
    rec_kernel<<<32, 512, REC_LDS, stream>>>(xg, Wp0f, Wp0b, hs0, cst, 0);
    xg_gemm<128, true><<<gxg, 256, 0, stream>>>(x, wb0f, wb0b, b_l0f, b_l0b, xg, 1);
    rec_kernel<<<32, 512, REC_LDS, stream>>>(xg, Wp0f, Wp0b, hs0, cst, 1);
    // ---- layer 1 ----
    xg_gemm<512, false><<<gxg, 256, 0, stream>>>(hs0, wb1f, wb1b, b_l1f, b_l1b, xg, 0);
    rec_kernel<<<32, 512, REC_LDS, stream>>>(xg, Wp1f, Wp1b, hs1, cst, 0);
    xg_gemm<512, false><<<gxg, 256, 0, stream>>>(hs0, wb1f, wb1b, b_l1f, b_l1b, xg, 1);
    rec_kernel<<<32, 512, REC_LDS, stream>>>(xg, Wp1f, Wp1b, hs1, cst, 1);

    // ---- attention + head ----
    dim3 g88(8, 8, 64);
    sgemm_scores<<<g88, 256, 0, stream>>>(hs1, S);
    softmax_rows<<<8192, 256, 0, stream>>>(S, P);
    transpose_nt<<<g88, 256, 0, stream>>>(hs1, hs1T);
    ctx_gemm<<<g88, 256, 0, stream>>>(P, hs1T, ctx);
    fc1_gemm<<<512, 256, 0, stream>>>(ctx, hs1, fc1wb, fc1b, fc1out);
    bn_stats<<<50, 256, 0, stream>>>(fc1out, stats);
    tail_kernel<<<128, 256, 0, stream>>>(fc1out, stats, bng, bnb, fc2w, fc2b,
                                         fc3w, fc3b, fc4w, fc4b, (float*)d_out);
    (void)in_sizes; (void)n_in; (void)out_size; (void)ws_size;
}